// Round 7
// baseline (595.598 us; speedup 1.0000x reference)
//
#include <hip/hip_runtime.h>

// Problem constants (fixed by the reference)
static constexpr int NN  = 50000;   // nodes (even)
static constexpr int EE  = 800000;  // edges
static constexpr int CIN = 96;      // input channels
static constexpr int L1C = 70, S1 = 72;  // TAG layer 1 out, padded stride
static constexpr int L2C = 43, S2 = 44;  // TAG layer 2 out, padded stride

// padded-weight workspace layout (floats)
static constexpr int W1P_OFF = 0;                    // 4 images of 96x72
static constexpr int W1P_IMG = CIN * S1;             // 6912
static constexpr int W2P_OFF = W1P_OFF + 4 * W1P_IMG;       // 27648; 4 images of 72x44
static constexpr int W2P_IMG = S1 * S2;              // 3168
static constexpr int WHP_OFF = W2P_OFF + 4 * W2P_IMG;       // 40320; 44x32
static constexpr int B1P_OFF = WHP_OFF + S2 * 32;    // 41728; 72
static constexpr int B2P_OFF = B1P_OFF + S1;         // 41800; 44
static constexpr int WSW_TOT = B2P_OFF + S2;         // 41844

// ---------------------------------------------------------------- preprocessing

__global__ void hist_kernel(const int* __restrict__ col, int* __restrict__ deg, int E) {
    int e = blockIdx.x * blockDim.x + threadIdx.x;
    if (e < E) atomicAdd(&deg[col[e]], 1);
}

static constexpr int SB = 256;  // scan block size

__global__ void reduce_kernel(const int* __restrict__ deg, int* __restrict__ bsum, int n) {
    __shared__ int sd[SB];
    int i = blockIdx.x * SB + threadIdx.x;
    sd[threadIdx.x] = (i < n) ? deg[i] : 0;
    __syncthreads();
    for (int s = SB / 2; s > 0; s >>= 1) {
        if (threadIdx.x < s) sd[threadIdx.x] += sd[threadIdx.x + s];
        __syncthreads();
    }
    if (threadIdx.x == 0) bsum[blockIdx.x] = sd[0];
}

__global__ void scan_sums_kernel(int* __restrict__ bsum, int nb) {
    __shared__ int sd[SB];
    int v = (threadIdx.x < nb) ? bsum[threadIdx.x] : 0;
    sd[threadIdx.x] = v;
    __syncthreads();
    for (int s = 1; s < SB; s <<= 1) {
        int t = (threadIdx.x >= s) ? sd[threadIdx.x - s] : 0;
        __syncthreads();
        sd[threadIdx.x] += t;
        __syncthreads();
    }
    if (threadIdx.x < nb) bsum[threadIdx.x] = sd[threadIdx.x] - v;  // exclusive
}

__global__ void block_scan_kernel(const int* __restrict__ deg, const int* __restrict__ bsum,
                                  int* __restrict__ off, int* __restrict__ cursor,
                                  float* __restrict__ dis, float* __restrict__ dis2, int n) {
    __shared__ int sd[SB];
    int i = blockIdx.x * SB + threadIdx.x;
    int v = (i < n) ? deg[i] : 0;
    sd[threadIdx.x] = v;
    __syncthreads();
    for (int s = 1; s < SB; s <<= 1) {
        int t = (threadIdx.x >= s) ? sd[threadIdx.x - s] : 0;
        __syncthreads();
        sd[threadIdx.x] += t;
        __syncthreads();
    }
    if (i < n) {
        int e = bsum[blockIdx.x] + sd[threadIdx.x] - v;
        off[i] = e;
        cursor[i] = e;
        dis[i]  = (v > 0) ? rsqrtf((float)v) : 0.0f;
        dis2[i] = rsqrtf((float)v + 1.0f);
        if (i == n - 1) off[n] = e + v;
    }
}

// pack (src, TAG weight) per edge; GCN weights are recomputed on the fly later.
__global__ void fill_kernel(const int* __restrict__ row, const int* __restrict__ col,
                            const float* __restrict__ dis, int* __restrict__ cursor,
                            int2* __restrict__ eTag, int E) {
    int e = blockIdx.x * blockDim.x + threadIdx.x;
    if (e < E) {
        int r = row[e], c = col[e];
        int pos = atomicAdd(&cursor[c], 1);
        eTag[pos] = make_int2(r, __float_as_int(dis[r] * dis[c]));
    }
}

// repack weights+biases into padded, 16B-aligned global images
__global__ void wpad_kernel(const float* __restrict__ W1, const float* __restrict__ b1,
                            const float* __restrict__ W2, const float* __restrict__ b2,
                            const float* __restrict__ Wmu, const float* __restrict__ Wls,
                            float* __restrict__ wsW) {
    int i = blockIdx.x * blockDim.x + threadIdx.x;
    if (i >= WSW_TOT) return;
    float val = 0.f;
    if (i < W2P_OFF) {
        int w = i / W1P_IMG, r = i - w * W1P_IMG;
        int k = r / S1, c = r - k * S1;
        if (c < L1C) val = W1[w * CIN * L1C + k * L1C + c];
    } else if (i < WHP_OFF) {
        int j = i - W2P_OFF;
        int w = j / W2P_IMG, r = j - w * W2P_IMG;
        int k = r / S2, c = r - k * S2;
        if (k < L1C && c < L2C) val = W2[w * L1C * L2C + k * L2C + c];
    } else if (i < B1P_OFF) {
        int j = i - WHP_OFF;
        int k = j >> 5, c = j & 31;
        if (k < L2C) val = (c < 16) ? Wmu[k * 16 + c] : Wls[k * 16 + (c - 16)];
    } else if (i < B2P_OFF) {
        int j = i - B1P_OFF;
        if (j < L1C) val = b1[j];
    } else {
        int j = i - B2P_OFF;
        if (j < L2C) val = b2[j];
    }
    wsW[i] = val;
}

// ------------------------------------------------------------- aggregation
// out[i][:] = (HASADD ? addv[i][:] : 0) + sum_e w_e * in[src_e][:]  (+ ReLU)
template <int C, bool HASADD, bool RELU>
__global__ void agg_kernel(const float* __restrict__ in, const float* addv,
                           float* out, const int* __restrict__ off,
                           const int2* __restrict__ ep, int n) {
    constexpr int TPN = C / 4;  // threads per node
    int t = blockIdx.x * blockDim.x + threadIdx.x;
    if (t >= n * TPN) return;
    int node = t / TPN;
    int cc = (t - node * TPN) * 4;
    int beg = off[node], end = off[node + 1];
    float4 a0 = make_float4(0.f, 0.f, 0.f, 0.f);
    float4 a1 = a0, a2 = a0, a3 = a0;
    int e = beg;
    for (; e + 4 <= end; e += 4) {
        int2 p0 = ep[e], p1 = ep[e + 1], p2 = ep[e + 2], p3 = ep[e + 3];
        float w0 = __int_as_float(p0.y), w1 = __int_as_float(p1.y);
        float w2 = __int_as_float(p2.y), w3 = __int_as_float(p3.y);
        float4 v0 = *reinterpret_cast<const float4*>(in + (size_t)p0.x * C + cc);
        float4 v1 = *reinterpret_cast<const float4*>(in + (size_t)p1.x * C + cc);
        float4 v2 = *reinterpret_cast<const float4*>(in + (size_t)p2.x * C + cc);
        float4 v3 = *reinterpret_cast<const float4*>(in + (size_t)p3.x * C + cc);
        a0.x += w0 * v0.x; a0.y += w0 * v0.y; a0.z += w0 * v0.z; a0.w += w0 * v0.w;
        a1.x += w1 * v1.x; a1.y += w1 * v1.y; a1.z += w1 * v1.z; a1.w += w1 * v1.w;
        a2.x += w2 * v2.x; a2.y += w2 * v2.y; a2.z += w2 * v2.z; a2.w += w2 * v2.w;
        a3.x += w3 * v3.x; a3.y += w3 * v3.y; a3.z += w3 * v3.z; a3.w += w3 * v3.w;
    }
    for (; e < end; ++e) {
        int2 p = ep[e];
        float w = __int_as_float(p.y);
        float4 v = *reinterpret_cast<const float4*>(in + (size_t)p.x * C + cc);
        a0.x += w * v.x; a0.y += w * v.y; a0.z += w * v.z; a0.w += w * v.w;
    }
    float4 r = make_float4(a0.x + a1.x + a2.x + a3.x, a0.y + a1.y + a2.y + a3.y,
                           a0.z + a1.z + a2.z + a3.z, a0.w + a1.w + a2.w + a3.w);
    if constexpr (HASADD) {
        float4 ad = *reinterpret_cast<const float4*>(addv + (size_t)node * C + cc);
        r.x += ad.x; r.y += ad.y; r.z += ad.z; r.w += ad.w;
    }
    if constexpr (RELU) {
        r.x = fmaxf(r.x, 0.f); r.y = fmaxf(r.y, 0.f);
        r.z = fmaxf(r.z, 0.f); r.w = fmaxf(r.w, 0.f);
    }
    *reinterpret_cast<float4*>(out + (size_t)node * C + cc) = r;
}

// GCN agg + self-loop + bias + split-store, fused final stage.
__global__ void agg_gcn_final_kernel(const float* __restrict__ yh,
                                     const int* __restrict__ off,
                                     const int2* __restrict__ ep,
                                     const float* __restrict__ dis2,
                                     const float* __restrict__ bmu,
                                     const float* __restrict__ bls,
                                     float* __restrict__ outp, int n) {
    int t = blockIdx.x * blockDim.x + threadIdx.x;
    if (t >= n * 8) return;
    int node = t >> 3;
    int cc = (t & 7) * 4;
    int beg = off[node], end = off[node + 1];
    float4 a0 = make_float4(0.f, 0.f, 0.f, 0.f);
    float4 a1 = a0;
    int e = beg;
    for (; e + 2 <= end; e += 2) {
        int s0 = ep[e].x, s1 = ep[e + 1].x;
        float w0 = dis2[s0], w1 = dis2[s1];
        float4 v0 = *reinterpret_cast<const float4*>(yh + (size_t)s0 * 32 + cc);
        float4 v1 = *reinterpret_cast<const float4*>(yh + (size_t)s1 * 32 + cc);
        a0.x += w0 * v0.x; a0.y += w0 * v0.y; a0.z += w0 * v0.z; a0.w += w0 * v0.w;
        a1.x += w1 * v1.x; a1.y += w1 * v1.y; a1.z += w1 * v1.z; a1.w += w1 * v1.w;
    }
    for (; e < end; ++e) {
        int s = ep[e].x;
        float w = dis2[s];
        float4 v = *reinterpret_cast<const float4*>(yh + (size_t)s * 32 + cc);
        a0.x += w * v.x; a0.y += w * v.y; a0.z += w * v.z; a0.w += w * v.w;
    }
    float d = dis2[node];
    float4 yv = *reinterpret_cast<const float4*>(yh + (size_t)node * 32 + cc);
    const float* bp = (cc < 16) ? (bmu + cc) : (bls + cc - 16);
    float4 r;
    r.x = d * (a0.x + a1.x) + d * d * yv.x + bp[0];
    r.y = d * (a0.y + a1.y) + d * d * yv.y + bp[1];
    r.z = d * (a0.z + a1.z) + d * d * yv.z + bp[2];
    r.w = d * (a0.w + a1.w) + d * d * yv.w + bp[3];
    size_t o = (cc < 16) ? ((size_t)node * 16 + cc)
                         : ((size_t)n * 16 + (size_t)node * 16 + (cc - 16));
    *reinterpret_cast<float4*>(outp + o) = r;
}

// ----------------------------------------------------------------- matmul
__device__ __forceinline__ void fma4(float4& a, float s, const float4& w) {
    a.x += s * w.x; a.y += s * w.y; a.z += s * w.z; a.w += s * w.w;
}

// Global-W fused matmul: out_w[n0..n0+1, c0..c0+3] = X[n0..n0+1, :] @ Wp_w (+bias on w=0).
// Wp: NW consecutive padded images (KR x PC, 16B-aligned, zero pads); no LDS ->
// residency is VGPR-limited (~8 blocks/CU), no fill prologue, 256-thread blocks.
// Weight lines are L1/L2-resident and broadcast across the wave's shared `pair`s.
template <int KR, int PC, int NW, bool BIAS>
__global__ void mmg_kernel(const float* __restrict__ X, const float* __restrict__ Wp,
                           const float* __restrict__ bp,
                           float* __restrict__ o0, float* __restrict__ o1, int n) {
    constexpr int CP4 = PC / 4;
    int idx = blockIdx.x * blockDim.x + threadIdx.x;
    if (idx >= (n >> 1) * CP4) return;
    int pair = idx / CP4;
    int c0 = (idx - pair * CP4) * 4;
    int n0 = pair * 2;
    const float* xa = X + (size_t)n0 * KR;
    const float* xb = xa + KR;
    const float* wc = Wp + c0;
    float4 acc[2][NW];
    #pragma unroll
    for (int w = 0; w < NW; ++w) {
        acc[0][w] = make_float4(0.f, 0.f, 0.f, 0.f);
        acc[1][w] = acc[0][w];
    }
    if constexpr (BIAS) {
        acc[0][0] = *reinterpret_cast<const float4*>(bp + c0);
        acc[1][0] = acc[0][0];
    }
    #pragma unroll 2
    for (int k4 = 0; k4 < KR / 4; ++k4) {
        float4 va = *reinterpret_cast<const float4*>(xa + k4 * 4);
        float4 vb = *reinterpret_cast<const float4*>(xb + k4 * 4);
        #pragma unroll
        for (int j = 0; j < 4; ++j) {
            int k = k4 * 4 + j;
            float sa = (&va.x)[j];
            float sb = (&vb.x)[j];
            #pragma unroll
            for (int w = 0; w < NW; ++w) {
                float4 wv = *reinterpret_cast<const float4*>(wc + ((size_t)w * KR + k) * PC);
                fma4(acc[0][w], sa, wv);
                fma4(acc[1][w], sb, wv);
            }
        }
    }
    float* outs[2] = {o0, o1};
    #pragma unroll
    for (int w = 0; w < NW; ++w) {
        float* o = outs[w] + (size_t)n0 * PC + c0;
        *reinterpret_cast<float4*>(o) = acc[0][w];
        *reinterpret_cast<float4*>(o + PC) = acc[1][w];
    }
}

// ------------------------------------------------------------------ launch

extern "C" void kernel_launch(void* const* d_in, const int* in_sizes, int n_in,
                              void* d_out, int out_size, void* d_ws, size_t ws_size,
                              hipStream_t stream) {
    const float* x   = (const float*)d_in[0];
    const int*   ei  = (const int*)d_in[1];
    const float* W1  = (const float*)d_in[2];
    const float* b1  = (const float*)d_in[3];
    const float* W2  = (const float*)d_in[4];
    const float* b2  = (const float*)d_in[5];
    const float* Wmu = (const float*)d_in[6];
    const float* bmu = (const float*)d_in[7];
    const float* Wls = (const float*)d_in[8];
    const float* bls = (const float*)d_in[9];
    float* out = (float*)d_out;

    const int N = NN, E = EE;
    const int* row = ei;
    const int* col = ei + E;

    // workspace carve-up (256B aligned)
    char* p = (char*)d_ws;
    auto alloc = [&](size_t bytes) -> char* {
        char* r = p;
        p += (bytes + 255) & ~(size_t)255;
        return r;
    };
    int*   deg    = (int*)alloc((size_t)N * 4);
    int*   off    = (int*)alloc((size_t)(N + 1) * 4);
    int*   cursor = (int*)alloc((size_t)N * 4);
    int*   bsum   = (int*)alloc((size_t)256 * 4);
    float* dis    = (float*)alloc((size_t)N * 4);
    float* dis2   = (float*)alloc((size_t)N * 4);
    float* wsW    = (float*)alloc((size_t)WSW_TOT * 4);
    int2*  eTag   = (int2*)alloc((size_t)E * 8);
    float* y0     = (float*)alloc((size_t)N * S1 * 4);
    float* y1     = (float*)alloc((size_t)N * S1 * 4);
    float* y2     = (float*)alloc((size_t)N * S1 * 4);
    float* y3     = (float*)alloc((size_t)N * S1 * 4);
    // overlay: u0..u3 (N*S2 each) live in y1..y3's space (y1..y3 dead by then)
    float* u0 = y1;
    float* u1 = u0 + (size_t)N * S2;
    float* u2 = u1 + (size_t)N * S2;
    float* u3 = u2 + (size_t)N * S2;
    // overlay: head output lives in u1's space (dead after layer-2 aggs)
    float* yh = u1;

    const float* W1p = wsW + W1P_OFF;
    const float* W2p = wsW + W2P_OFF;
    const float* Whp = wsW + WHP_OFF;
    const float* b1p = wsW + B1P_OFF;
    const float* b2p = wsW + B2P_OFF;

    const int B = 256;
    int gE = (E + B - 1) / B;
    int nb = (N + SB - 1) / SB;  // 196 scan blocks

    // --- graph preprocessing -> CSR by destination (+ weight repack)
    hipMemsetAsync(deg, 0, (size_t)N * 4, stream);
    wpad_kernel<<<(WSW_TOT + B - 1) / B, B, 0, stream>>>(W1, b1, W2, b2, Wmu, Wls, wsW);
    hist_kernel<<<gE, B, 0, stream>>>(col, deg, E);
    reduce_kernel<<<nb, SB, 0, stream>>>(deg, bsum, N);
    scan_sums_kernel<<<1, SB, 0, stream>>>(bsum, nb);
    block_scan_kernel<<<nb, SB, 0, stream>>>(deg, bsum, off, cursor, dis, dis2, N);
    fill_kernel<<<gE, B, 0, stream>>>(row, col, dis, cursor, eTag, E);

    // grids
    int gm1 = ((N / 2) * (S1 / 4) + B - 1) / B;  // 1758
    int gm2 = ((N / 2) * (S2 / 4) + B - 1) / B;  // 1075
    int gmh = ((N / 2) * 8 + B - 1) / B;         // 782
    int ga72 = (N * (S1 / 4) + B - 1) / B;
    int ga44 = (N * (S2 / 4) + B - 1) / B;
    int ga32 = (N * 8 + B - 1) / B;

    // --- TAG layer 1 via Horner: o1 = relu(y0 + A(y1 + A(y2 + A*y3)))
    mmg_kernel<CIN, S1, 2, true ><<<gm1, B, 0, stream>>>(x, W1p,               b1p, y0, y1, N);
    mmg_kernel<CIN, S1, 2, false><<<gm1, B, 0, stream>>>(x, W1p + 2 * W1P_IMG, nullptr, y2, y3, N);
    agg_kernel<S1, true, false><<<ga72, B, 0, stream>>>(y3, y2, y2, off, eTag, N);
    agg_kernel<S1, true, false><<<ga72, B, 0, stream>>>(y2, y1, y1, off, eTag, N);
    agg_kernel<S1, true, true ><<<ga72, B, 0, stream>>>(y1, y0, y0, off, eTag, N);
    // o1 = y0 (stride S1, pad cols zero)

    // --- TAG layer 2 via Horner: o2 = relu(u0 + A(u1 + A(u2 + A*u3)))
    mmg_kernel<S1, S2, 2, true ><<<gm2, B, 0, stream>>>(y0, W2p,               b2p, u0, u1, N);
    mmg_kernel<S1, S2, 2, false><<<gm2, B, 0, stream>>>(y0, W2p + 2 * W2P_IMG, nullptr, u2, u3, N);
    agg_kernel<S2, true, false><<<ga44, B, 0, stream>>>(u3, u2, u2, off, eTag, N);
    agg_kernel<S2, true, false><<<ga44, B, 0, stream>>>(u2, u1, u1, off, eTag, N);
    agg_kernel<S2, true, true ><<<ga44, B, 0, stream>>>(u1, u0, u0, off, eTag, N);
    // o2 = u0 (stride S2, pad col zero)

    // --- GCN heads: head matmul (global-W), then fused agg+self+bias+split-store
    mmg_kernel<S2, 32, 1, false><<<gmh, B, 0, stream>>>(u0, Whp, nullptr, yh, nullptr, N);
    agg_gcn_final_kernel<<<ga32, B, 0, stream>>>(yh, off, eTag, dis2, bmu, bls, out, N);
}

// Round 8
// 499.355 us; speedup vs baseline: 1.1927x; 1.1927x over previous
//
#include <hip/hip_runtime.h>

// Problem constants (fixed by the reference)
static constexpr int NN  = 50000;   // nodes (even)
static constexpr int EE  = 800000;  // edges
static constexpr int CIN = 96;      // input channels
static constexpr int L1C = 70, S1 = 72;  // TAG layer 1 out, padded stride
static constexpr int L2C = 43, S2 = 44;  // TAG layer 2 out, padded stride

// bf16 weight image sizes (in uints = 2 bf16)
static constexpr int IMG1U = CIN * S1 / 2;   // 3456
static constexpr int IMG2U = S1 * S2 / 2;    // 1584
static constexpr int IMGHU = S2 * 32 / 2;    // 704
static constexpr int NU1 = 4 * IMG1U;        // 13824
static constexpr int NU2 = 4 * IMG2U;        // 6336
static constexpr int TUW = NU1 + NU2 + IMGHU; // 20864 uints
static constexpr int NBF = S1 + S2;          // bias floats (72 + 44)

// ------------------------------------------------------------ bf16 helpers
__device__ __forceinline__ float bf_lo(unsigned int u) {
    return __uint_as_float(u << 16);
}
__device__ __forceinline__ float bf_hi(unsigned int u) {
    return __uint_as_float(u & 0xffff0000u);
}
__device__ __forceinline__ unsigned int bf_rne_bits(float f) {
    unsigned int u = __float_as_uint(f);
    return u + 0x7fffu + ((u >> 16) & 1u);
}
__device__ __forceinline__ unsigned int pack_bf(float a, float b) {
    return (bf_rne_bits(a) >> 16) | (bf_rne_bits(b) & 0xffff0000u);
}
__device__ __forceinline__ float4 unpack_bf4(uint2 q) {
    return make_float4(bf_lo(q.x), bf_hi(q.x), bf_lo(q.y), bf_hi(q.y));
}

// ---------------------------------------------------------------- preprocessing

__global__ void hist_kernel(const int* __restrict__ col, int* __restrict__ deg, int E) {
    int e = blockIdx.x * blockDim.x + threadIdx.x;
    if (e < E) atomicAdd(&deg[col[e]], 1);
}

static constexpr int SB = 256;  // scan block size

__global__ void reduce_kernel(const int* __restrict__ deg, int* __restrict__ bsum, int n) {
    __shared__ int sd[SB];
    int i = blockIdx.x * SB + threadIdx.x;
    sd[threadIdx.x] = (i < n) ? deg[i] : 0;
    __syncthreads();
    for (int s = SB / 2; s > 0; s >>= 1) {
        if (threadIdx.x < s) sd[threadIdx.x] += sd[threadIdx.x + s];
        __syncthreads();
    }
    if (threadIdx.x == 0) bsum[blockIdx.x] = sd[0];
}

__global__ void scan_sums_kernel(int* __restrict__ bsum, int nb) {
    __shared__ int sd[SB];
    int v = (threadIdx.x < nb) ? bsum[threadIdx.x] : 0;
    sd[threadIdx.x] = v;
    __syncthreads();
    for (int s = 1; s < SB; s <<= 1) {
        int t = (threadIdx.x >= s) ? sd[threadIdx.x - s] : 0;
        __syncthreads();
        sd[threadIdx.x] += t;
        __syncthreads();
    }
    if (threadIdx.x < nb) bsum[threadIdx.x] = sd[threadIdx.x] - v;  // exclusive
}

__global__ void block_scan_kernel(const int* __restrict__ deg, const int* __restrict__ bsum,
                                  int* __restrict__ off, int* __restrict__ cursor,
                                  float* __restrict__ dis, float* __restrict__ dis2, int n) {
    __shared__ int sd[SB];
    int i = blockIdx.x * SB + threadIdx.x;
    int v = (i < n) ? deg[i] : 0;
    sd[threadIdx.x] = v;
    __syncthreads();
    for (int s = 1; s < SB; s <<= 1) {
        int t = (threadIdx.x >= s) ? sd[threadIdx.x - s] : 0;
        __syncthreads();
        sd[threadIdx.x] += t;
        __syncthreads();
    }
    if (i < n) {
        int e = bsum[blockIdx.x] + sd[threadIdx.x] - v;
        off[i] = e;
        cursor[i] = e;
        dis[i]  = (v > 0) ? rsqrtf((float)v) : 0.0f;
        dis2[i] = rsqrtf((float)v + 1.0f);
        if (i == n - 1) off[n] = e + v;
    }
}

// pack (src, TAG weight) per edge; GCN weights recomputed on the fly later.
__global__ void fill_kernel(const int* __restrict__ row, const int* __restrict__ col,
                            const float* __restrict__ dis, int* __restrict__ cursor,
                            int2* __restrict__ eTag, int E) {
    int e = blockIdx.x * blockDim.x + threadIdx.x;
    if (e < E) {
        int r = row[e], c = col[e];
        int pos = atomicAdd(&cursor[c], 1);
        eTag[pos] = make_int2(r, __float_as_int(dis[r] * dis[c]));
    }
}

// repack weights into padded bf16 global images + padded fp32 biases
__global__ void wpad_kernel(const float* __restrict__ W1, const float* __restrict__ b1,
                            const float* __restrict__ W2, const float* __restrict__ b2,
                            const float* __restrict__ Wmu, const float* __restrict__ Wls,
                            unsigned int* __restrict__ wB, float* __restrict__ bB) {
    int i = blockIdx.x * blockDim.x + threadIdx.x;
    if (i < TUW) {
        float v0 = 0.f, v1 = 0.f;
        if (i < NU1) {
            int img = i / IMG1U, r = i - img * IMG1U;
            int k = r / (S1 / 2), c0 = (r - k * (S1 / 2)) * 2;
            const float* Wi = W1 + (size_t)img * CIN * L1C + (size_t)k * L1C;
            if (c0 < L1C) v0 = Wi[c0];
            if (c0 + 1 < L1C) v1 = Wi[c0 + 1];
        } else if (i < NU1 + NU2) {
            int j = i - NU1;
            int img = j / IMG2U, r = j - img * IMG2U;
            int k = r / (S2 / 2), c0 = (r - k * (S2 / 2)) * 2;
            if (k < L1C) {
                const float* Wi = W2 + (size_t)img * L1C * L2C + (size_t)k * L2C;
                if (c0 < L2C) v0 = Wi[c0];
                if (c0 + 1 < L2C) v1 = Wi[c0 + 1];
            }
        } else {
            int j = i - NU1 - NU2;
            int k = j / 16, c0 = (j - k * 16) * 2;  // 32 cols -> 16 uints per row
            if (k < L2C) {
                v0 = (c0 < 16) ? Wmu[k * 16 + c0] : Wls[k * 16 + (c0 - 16)];
                int c1 = c0 + 1;
                v1 = (c1 < 16) ? Wmu[k * 16 + c1] : Wls[k * 16 + (c1 - 16)];
            }
        }
        wB[i] = pack_bf(v0, v1);
    } else if (i < TUW + NBF) {
        int j = i - TUW;
        float v = 0.f;
        if (j < S1) { if (j < L1C) v = b1[j]; }
        else { int k = j - S1; if (k < L2C) v = b2[k]; }
        bB[j] = v;
    }
}

// ------------------------------------------------------------- aggregation (bf16)
// out[i][:] = (HASADD ? addv[i][:] : 0) + sum_e w_e * in[src_e][:]  (+ ReLU)
// bf16 storage, fp32 accumulate. In-place safe for out==addv.
template <int C, bool HASADD, bool RELU>
__global__ void aggb_kernel(const unsigned short* __restrict__ in, const unsigned short* addv,
                            unsigned short* out, const int* __restrict__ off,
                            const int2* __restrict__ ep, int n) {
    constexpr int TPN = C / 4;  // threads per node (4 bf16 channels each)
    int t = blockIdx.x * blockDim.x + threadIdx.x;
    if (t >= n * TPN) return;
    int node = t / TPN;
    int cc = (t - node * TPN) * 4;
    int beg = off[node], end = off[node + 1];
    float4 a0 = make_float4(0.f, 0.f, 0.f, 0.f);
    float4 a1 = a0, a2 = a0, a3 = a0;
    int e = beg;
    for (; e + 4 <= end; e += 4) {
        int2 p0 = ep[e], p1 = ep[e + 1], p2 = ep[e + 2], p3 = ep[e + 3];
        float w0 = __int_as_float(p0.y), w1 = __int_as_float(p1.y);
        float w2 = __int_as_float(p2.y), w3 = __int_as_float(p3.y);
        uint2 q0 = *reinterpret_cast<const uint2*>(in + (size_t)p0.x * C + cc);
        uint2 q1 = *reinterpret_cast<const uint2*>(in + (size_t)p1.x * C + cc);
        uint2 q2 = *reinterpret_cast<const uint2*>(in + (size_t)p2.x * C + cc);
        uint2 q3 = *reinterpret_cast<const uint2*>(in + (size_t)p3.x * C + cc);
        float4 v0 = unpack_bf4(q0), v1 = unpack_bf4(q1);
        float4 v2 = unpack_bf4(q2), v3 = unpack_bf4(q3);
        a0.x += w0 * v0.x; a0.y += w0 * v0.y; a0.z += w0 * v0.z; a0.w += w0 * v0.w;
        a1.x += w1 * v1.x; a1.y += w1 * v1.y; a1.z += w1 * v1.z; a1.w += w1 * v1.w;
        a2.x += w2 * v2.x; a2.y += w2 * v2.y; a2.z += w2 * v2.z; a2.w += w2 * v2.w;
        a3.x += w3 * v3.x; a3.y += w3 * v3.y; a3.z += w3 * v3.z; a3.w += w3 * v3.w;
    }
    for (; e < end; ++e) {
        int2 p = ep[e];
        float w = __int_as_float(p.y);
        float4 v = unpack_bf4(*reinterpret_cast<const uint2*>(in + (size_t)p.x * C + cc));
        a0.x += w * v.x; a0.y += w * v.y; a0.z += w * v.z; a0.w += w * v.w;
    }
    float4 r = make_float4(a0.x + a1.x + a2.x + a3.x, a0.y + a1.y + a2.y + a3.y,
                           a0.z + a1.z + a2.z + a3.z, a0.w + a1.w + a2.w + a3.w);
    if constexpr (HASADD) {
        float4 ad = unpack_bf4(*reinterpret_cast<const uint2*>(addv + (size_t)node * C + cc));
        r.x += ad.x; r.y += ad.y; r.z += ad.z; r.w += ad.w;
    }
    if constexpr (RELU) {
        r.x = fmaxf(r.x, 0.f); r.y = fmaxf(r.y, 0.f);
        r.z = fmaxf(r.z, 0.f); r.w = fmaxf(r.w, 0.f);
    }
    *reinterpret_cast<uint2*>(out + (size_t)node * C + cc) =
        make_uint2(pack_bf(r.x, r.y), pack_bf(r.z, r.w));
}

// GCN agg + self-loop + bias + split-store, fused final stage (fp32 yh for precision).
__global__ void agg_gcn_final_kernel(const float* __restrict__ yh,
                                     const int* __restrict__ off,
                                     const int2* __restrict__ ep,
                                     const float* __restrict__ dis2,
                                     const float* __restrict__ bmu,
                                     const float* __restrict__ bls,
                                     float* __restrict__ outp, int n) {
    int t = blockIdx.x * blockDim.x + threadIdx.x;
    if (t >= n * 8) return;
    int node = t >> 3;
    int cc = (t & 7) * 4;
    int beg = off[node], end = off[node + 1];
    float4 a0 = make_float4(0.f, 0.f, 0.f, 0.f);
    float4 a1 = a0;
    int e = beg;
    for (; e + 2 <= end; e += 2) {
        int s0 = ep[e].x, s1 = ep[e + 1].x;
        float w0 = dis2[s0], w1 = dis2[s1];
        float4 v0 = *reinterpret_cast<const float4*>(yh + (size_t)s0 * 32 + cc);
        float4 v1 = *reinterpret_cast<const float4*>(yh + (size_t)s1 * 32 + cc);
        a0.x += w0 * v0.x; a0.y += w0 * v0.y; a0.z += w0 * v0.z; a0.w += w0 * v0.w;
        a1.x += w1 * v1.x; a1.y += w1 * v1.y; a1.z += w1 * v1.z; a1.w += w1 * v1.w;
    }
    for (; e < end; ++e) {
        int s = ep[e].x;
        float w = dis2[s];
        float4 v = *reinterpret_cast<const float4*>(yh + (size_t)s * 32 + cc);
        a0.x += w * v.x; a0.y += w * v.y; a0.z += w * v.z; a0.w += w * v.w;
    }
    float d = dis2[node];
    float4 yv = *reinterpret_cast<const float4*>(yh + (size_t)node * 32 + cc);
    const float* bp = (cc < 16) ? (bmu + cc) : (bls + cc - 16);
    float4 r;
    r.x = d * (a0.x + a1.x) + d * d * yv.x + bp[0];
    r.y = d * (a0.y + a1.y) + d * d * yv.y + bp[1];
    r.z = d * (a0.z + a1.z) + d * d * yv.z + bp[2];
    r.w = d * (a0.w + a1.w) + d * d * yv.w + bp[3];
    size_t o = (cc < 16) ? ((size_t)node * 16 + cc)
                         : ((size_t)n * 16 + (size_t)node * 16 + (cc - 16));
    *reinterpret_cast<float4*>(outp + o) = r;
}

// ----------------------------------------------------------------- matmul
__device__ __forceinline__ void fma4(float4& a, float s, const float4& w) {
    a.x += s * w.x; a.y += s * w.y; a.z += s * w.z; a.w += s * w.w;
}

// Fused multi-W matmul, bf16 weights (global, L1/L2-resident), fp32 accumulate.
// out_w[n0..n0+1, c0..c0+3] = X[n0..n0+1, :] @ W_w (+bias on w=0).
// XBF: X rows are bf16 (stride KR elems); OBF: outputs stored bf16.
template <int KR, int PC, int NW, bool XBF, bool OBF, bool BIAS>
__global__ void mmb_kernel(const void* __restrict__ Xv, const unsigned int* __restrict__ Wp,
                           const float* __restrict__ bp,
                           void* __restrict__ o0v, void* __restrict__ o1v, int n) {
    constexpr int CP4 = PC / 4;
    constexpr int PCU = PC / 2;
    int idx = blockIdx.x * blockDim.x + threadIdx.x;
    if (idx >= (n >> 1) * CP4) return;
    int pair = idx / CP4;
    int c0 = (idx - pair * CP4) * 4;
    int n0 = pair * 2;
    const float* xaf = (const float*)Xv + (size_t)n0 * KR;
    const float* xbf = xaf + KR;
    const unsigned short* xah = (const unsigned short*)Xv + (size_t)n0 * KR;
    const unsigned short* xbh = xah + KR;
    const unsigned int* wc = Wp + (c0 >> 1);
    float4 acc[2][NW];
    #pragma unroll
    for (int w = 0; w < NW; ++w) {
        acc[0][w] = make_float4(0.f, 0.f, 0.f, 0.f);
        acc[1][w] = acc[0][w];
    }
    if constexpr (BIAS) {
        acc[0][0] = *reinterpret_cast<const float4*>(bp + c0);
        acc[1][0] = acc[0][0];
    }
    #pragma unroll 2
    for (int k4 = 0; k4 < KR / 4; ++k4) {
        float4 va, vb;
        if constexpr (XBF) {
            va = unpack_bf4(*reinterpret_cast<const uint2*>(xah + k4 * 4));
            vb = unpack_bf4(*reinterpret_cast<const uint2*>(xbh + k4 * 4));
        } else {
            va = *reinterpret_cast<const float4*>(xaf + k4 * 4);
            vb = *reinterpret_cast<const float4*>(xbf + k4 * 4);
        }
        #pragma unroll
        for (int j = 0; j < 4; ++j) {
            int k = k4 * 4 + j;
            float sa = (&va.x)[j];
            float sb = (&vb.x)[j];
            #pragma unroll
            for (int w = 0; w < NW; ++w) {
                uint2 q = *reinterpret_cast<const uint2*>(wc + (size_t)(w * KR + k) * PCU);
                float4 wv = unpack_bf4(q);
                fma4(acc[0][w], sa, wv);
                fma4(acc[1][w], sb, wv);
            }
        }
    }
    void* outs[2] = {o0v, o1v};
    #pragma unroll
    for (int w = 0; w < NW; ++w) {
        if constexpr (OBF) {
            unsigned short* o = (unsigned short*)outs[w] + (size_t)n0 * PC + c0;
            *reinterpret_cast<uint2*>(o) =
                make_uint2(pack_bf(acc[0][w].x, acc[0][w].y), pack_bf(acc[0][w].z, acc[0][w].w));
            *reinterpret_cast<uint2*>(o + PC) =
                make_uint2(pack_bf(acc[1][w].x, acc[1][w].y), pack_bf(acc[1][w].z, acc[1][w].w));
        } else {
            float* o = (float*)outs[w] + (size_t)n0 * PC + c0;
            *reinterpret_cast<float4*>(o) = acc[0][w];
            *reinterpret_cast<float4*>(o + PC) = acc[1][w];
        }
    }
}

// ------------------------------------------------------------------ launch

extern "C" void kernel_launch(void* const* d_in, const int* in_sizes, int n_in,
                              void* d_out, int out_size, void* d_ws, size_t ws_size,
                              hipStream_t stream) {
    const float* x   = (const float*)d_in[0];
    const int*   ei  = (const int*)d_in[1];
    const float* W1  = (const float*)d_in[2];
    const float* b1  = (const float*)d_in[3];
    const float* W2  = (const float*)d_in[4];
    const float* b2  = (const float*)d_in[5];
    const float* Wmu = (const float*)d_in[6];
    const float* bmu = (const float*)d_in[7];
    const float* Wls = (const float*)d_in[8];
    const float* bls = (const float*)d_in[9];
    float* out = (float*)d_out;

    const int N = NN, E = EE;
    const int* row = ei;
    const int* col = ei + E;

    // workspace carve-up (256B aligned)
    char* p = (char*)d_ws;
    auto alloc = [&](size_t bytes) -> char* {
        char* r = p;
        p += (bytes + 255) & ~(size_t)255;
        return r;
    };
    int*   deg    = (int*)alloc((size_t)N * 4);
    int*   off    = (int*)alloc((size_t)(N + 1) * 4);
    int*   cursor = (int*)alloc((size_t)N * 4);
    int*   bsum   = (int*)alloc((size_t)256 * 4);
    float* dis    = (float*)alloc((size_t)N * 4);
    float* dis2   = (float*)alloc((size_t)N * 4);
    unsigned int* wB = (unsigned int*)alloc((size_t)TUW * 4);
    float* bB     = (float*)alloc((size_t)NBF * 4);
    int2*  eTag   = (int2*)alloc((size_t)E * 8);
    unsigned short* y0 = (unsigned short*)alloc((size_t)N * S1 * 2);
    unsigned short* y1 = (unsigned short*)alloc((size_t)N * S1 * 2);
    unsigned short* y2 = (unsigned short*)alloc((size_t)N * S1 * 2);
    unsigned short* y3 = (unsigned short*)alloc((size_t)N * S1 * 2);
    unsigned short* u0 = (unsigned short*)alloc((size_t)N * S2 * 2);
    unsigned short* u1 = (unsigned short*)alloc((size_t)N * S2 * 2);
    unsigned short* u2 = (unsigned short*)alloc((size_t)N * S2 * 2);
    unsigned short* u3 = (unsigned short*)alloc((size_t)N * S2 * 2);
    float* yh     = (float*)alloc((size_t)N * 32 * 4);

    const unsigned int* W1b = wB;
    const unsigned int* W2b = wB + NU1;
    const unsigned int* Whb = wB + NU1 + NU2;
    const float* b1p = bB;
    const float* b2p = bB + S1;

    const int B = 256;
    int gE = (E + B - 1) / B;
    int nb = (N + SB - 1) / SB;  // 196 scan blocks

    // --- graph preprocessing -> CSR by destination (+ weight repack to bf16)
    hipMemsetAsync(deg, 0, (size_t)N * 4, stream);
    wpad_kernel<<<(TUW + NBF + B - 1) / B, B, 0, stream>>>(W1, b1, W2, b2, Wmu, Wls, wB, bB);
    hist_kernel<<<gE, B, 0, stream>>>(col, deg, E);
    reduce_kernel<<<nb, SB, 0, stream>>>(deg, bsum, N);
    scan_sums_kernel<<<1, SB, 0, stream>>>(bsum, nb);
    block_scan_kernel<<<nb, SB, 0, stream>>>(deg, bsum, off, cursor, dis, dis2, N);
    fill_kernel<<<gE, B, 0, stream>>>(row, col, dis, cursor, eTag, E);

    // grids
    int gm1 = ((N / 2) * (S1 / 4) + B - 1) / B;  // 1758
    int gm2 = ((N / 2) * (S2 / 4) + B - 1) / B;  // 1075
    int gmh = ((N / 2) * 8 + B - 1) / B;         // 782
    int ga72 = (N * (S1 / 4) + B - 1) / B;
    int ga44 = (N * (S2 / 4) + B - 1) / B;
    int ga32 = (N * 8 + B - 1) / B;

    // --- TAG layer 1 via Horner: o1 = relu(y0 + A(y1 + A(y2 + A*y3)))
    mmb_kernel<CIN, S1, 2, false, true, true ><<<gm1, B, 0, stream>>>(x, W1b,             b1p, y0, y1, N);
    mmb_kernel<CIN, S1, 2, false, true, false><<<gm1, B, 0, stream>>>(x, W1b + 2 * IMG1U, nullptr, y2, y3, N);
    aggb_kernel<S1, true, false><<<ga72, B, 0, stream>>>(y3, y2, y2, off, eTag, N);
    aggb_kernel<S1, true, false><<<ga72, B, 0, stream>>>(y2, y1, y1, off, eTag, N);
    aggb_kernel<S1, true, true ><<<ga72, B, 0, stream>>>(y1, y0, y0, off, eTag, N);
    // o1 = y0 (bf16, stride S1, pad cols zero)

    // --- TAG layer 2 via Horner: o2 = relu(u0 + A(u1 + A(u2 + A*u3)))
    mmb_kernel<S1, S2, 2, true, true, true ><<<gm2, B, 0, stream>>>(y0, W2b,             b2p, u0, u1, N);
    mmb_kernel<S1, S2, 2, true, true, false><<<gm2, B, 0, stream>>>(y0, W2b + 2 * IMG2U, nullptr, u2, u3, N);
    aggb_kernel<S2, true, false><<<ga44, B, 0, stream>>>(u3, u2, u2, off, eTag, N);
    aggb_kernel<S2, true, false><<<ga44, B, 0, stream>>>(u2, u1, u1, off, eTag, N);
    aggb_kernel<S2, true, true ><<<ga44, B, 0, stream>>>(u1, u0, u0, off, eTag, N);
    // o2 = u0 (bf16, stride S2, pad col zero)

    // --- GCN heads: head matmul (bf16 in, fp32 out), then fused final agg
    mmb_kernel<S2, 32, 1, true, false, false><<<gmh, B, 0, stream>>>(u0, Whb, nullptr, yh, nullptr, N);
    agg_gcn_final_kernel<<<ga32, B, 0, stream>>>(yh, off, eTag, dis2, bmu, bls, out, N);
}

// Round 9
// 423.491 us; speedup vs baseline: 1.4064x; 1.1791x over previous
//
#include <hip/hip_runtime.h>

// Problem constants (fixed by the reference)
static constexpr int NN  = 50000;   // nodes (even)
static constexpr int EE  = 800000;  // edges
static constexpr int CIN = 96;      // input channels
static constexpr int L1C = 70, S1 = 72;  // TAG layer 1 out, padded stride
static constexpr int L2C = 43, S2 = 44;  // TAG layer 2 out, padded stride

// bf16 weight image sizes (in uints = 2 bf16)
static constexpr int IMG1U = CIN * S1 / 2;   // 3456
static constexpr int IMG2U = S1 * S2 / 2;    // 1584
static constexpr int IMGHU = S2 * 32 / 2;    // 704
static constexpr int NU1 = 4 * IMG1U;        // 13824
static constexpr int NU2 = 4 * IMG2U;        // 6336
static constexpr int TUW = NU1 + NU2 + IMGHU; // 20864 uints
static constexpr int NBF = S1 + S2;          // bias floats (72 + 44)

// ------------------------------------------------------------ bf16 helpers
__device__ __forceinline__ float bf_lo(unsigned int u) {
    return __uint_as_float(u << 16);
}
__device__ __forceinline__ float bf_hi(unsigned int u) {
    return __uint_as_float(u & 0xffff0000u);
}
__device__ __forceinline__ unsigned int bf_rne_bits(float f) {
    unsigned int u = __float_as_uint(f);
    return u + 0x7fffu + ((u >> 16) & 1u);
}
__device__ __forceinline__ unsigned int pack_bf(float a, float b) {
    return (bf_rne_bits(a) >> 16) | (bf_rne_bits(b) & 0xffff0000u);
}
__device__ __forceinline__ float4 unpack_bf4(uint2 q) {
    return make_float4(bf_lo(q.x), bf_hi(q.x), bf_lo(q.y), bf_hi(q.y));
}

// ---------------------------------------------------------------- preprocessing

__global__ void hist_kernel(const int* __restrict__ col, int* __restrict__ deg, int E) {
    int e = blockIdx.x * blockDim.x + threadIdx.x;
    if (e < E) atomicAdd(&deg[col[e]], 1);
}

static constexpr int SB = 256;  // scan block size

__global__ void reduce_kernel(const int* __restrict__ deg, int* __restrict__ bsum, int n) {
    __shared__ int sd[SB];
    int i = blockIdx.x * SB + threadIdx.x;
    sd[threadIdx.x] = (i < n) ? deg[i] : 0;
    __syncthreads();
    for (int s = SB / 2; s > 0; s >>= 1) {
        if (threadIdx.x < s) sd[threadIdx.x] += sd[threadIdx.x + s];
        __syncthreads();
    }
    if (threadIdx.x == 0) bsum[blockIdx.x] = sd[0];
}

__global__ void scan_sums_kernel(int* __restrict__ bsum, int nb) {
    __shared__ int sd[SB];
    int v = (threadIdx.x < nb) ? bsum[threadIdx.x] : 0;
    sd[threadIdx.x] = v;
    __syncthreads();
    for (int s = 1; s < SB; s <<= 1) {
        int t = (threadIdx.x >= s) ? sd[threadIdx.x - s] : 0;
        __syncthreads();
        sd[threadIdx.x] += t;
        __syncthreads();
    }
    if (threadIdx.x < nb) bsum[threadIdx.x] = sd[threadIdx.x] - v;  // exclusive
}

__global__ void block_scan_kernel(const int* __restrict__ deg, const int* __restrict__ bsum,
                                  int* __restrict__ off, int* __restrict__ cursor,
                                  float* __restrict__ dis, float* __restrict__ dis2, int n) {
    __shared__ int sd[SB];
    int i = blockIdx.x * SB + threadIdx.x;
    int v = (i < n) ? deg[i] : 0;
    sd[threadIdx.x] = v;
    __syncthreads();
    for (int s = 1; s < SB; s <<= 1) {
        int t = (threadIdx.x >= s) ? sd[threadIdx.x - s] : 0;
        __syncthreads();
        sd[threadIdx.x] += t;
        __syncthreads();
    }
    if (i < n) {
        int e = bsum[blockIdx.x] + sd[threadIdx.x] - v;
        off[i] = e;
        cursor[i] = e;
        dis[i]  = (v > 0) ? rsqrtf((float)v) : 0.0f;
        dis2[i] = rsqrtf((float)v + 1.0f);
        if (i == n - 1) off[n] = e + v;
    }
}

// pack (src, TAG weight) per edge; GCN weights recomputed on the fly later.
__global__ void fill_kernel(const int* __restrict__ row, const int* __restrict__ col,
                            const float* __restrict__ dis, int* __restrict__ cursor,
                            int2* __restrict__ eTag, int E) {
    int e = blockIdx.x * blockDim.x + threadIdx.x;
    if (e < E) {
        int r = row[e], c = col[e];
        int pos = atomicAdd(&cursor[c], 1);
        eTag[pos] = make_int2(r, __float_as_int(dis[r] * dis[c]));
    }
}

// repack weights into padded bf16 global images + padded fp32 biases
__global__ void wpad_kernel(const float* __restrict__ W1, const float* __restrict__ b1,
                            const float* __restrict__ W2, const float* __restrict__ b2,
                            const float* __restrict__ Wmu, const float* __restrict__ Wls,
                            unsigned int* __restrict__ wB, float* __restrict__ bB) {
    int i = blockIdx.x * blockDim.x + threadIdx.x;
    if (i < TUW) {
        float v0 = 0.f, v1 = 0.f;
        if (i < NU1) {
            int img = i / IMG1U, r = i - img * IMG1U;
            int k = r / (S1 / 2), c0 = (r - k * (S1 / 2)) * 2;
            const float* Wi = W1 + (size_t)img * CIN * L1C + (size_t)k * L1C;
            if (c0 < L1C) v0 = Wi[c0];
            if (c0 + 1 < L1C) v1 = Wi[c0 + 1];
        } else if (i < NU1 + NU2) {
            int j = i - NU1;
            int img = j / IMG2U, r = j - img * IMG2U;
            int k = r / (S2 / 2), c0 = (r - k * (S2 / 2)) * 2;
            if (k < L1C) {
                const float* Wi = W2 + (size_t)img * L1C * L2C + (size_t)k * L2C;
                if (c0 < L2C) v0 = Wi[c0];
                if (c0 + 1 < L2C) v1 = Wi[c0 + 1];
            }
        } else {
            int j = i - NU1 - NU2;
            int k = j / 16, c0 = (j - k * 16) * 2;  // 32 cols -> 16 uints per row
            if (k < L2C) {
                v0 = (c0 < 16) ? Wmu[k * 16 + c0] : Wls[k * 16 + (c0 - 16)];
                int c1 = c0 + 1;
                v1 = (c1 < 16) ? Wmu[k * 16 + c1] : Wls[k * 16 + (c1 - 16)];
            }
        }
        wB[i] = pack_bf(v0, v1);
    } else if (i < TUW + NBF) {
        int j = i - TUW;
        float v = 0.f;
        if (j < S1) { if (j < L1C) v = b1[j]; }
        else { int k = j - S1; if (k < L2C) v = b2[k]; }
        bB[j] = v;
    }
}

// ------------------------------------------------------------- aggregation (bf16)
// out[i][:] = (HASADD ? addv[i][:] : 0) + sum_e w_e * in[src_e][:]  (+ ReLU)
// bf16 storage, fp32 accumulate. In-place safe for out==addv.
template <int C, bool HASADD, bool RELU>
__global__ void aggb_kernel(const unsigned short* __restrict__ in, const unsigned short* addv,
                            unsigned short* out, const int* __restrict__ off,
                            const int2* __restrict__ ep, int n) {
    constexpr int TPN = C / 4;  // threads per node (4 bf16 channels each)
    int t = blockIdx.x * blockDim.x + threadIdx.x;
    if (t >= n * TPN) return;
    int node = t / TPN;
    int cc = (t - node * TPN) * 4;
    int beg = off[node], end = off[node + 1];
    float4 a0 = make_float4(0.f, 0.f, 0.f, 0.f);
    float4 a1 = a0, a2 = a0, a3 = a0;
    int e = beg;
    for (; e + 4 <= end; e += 4) {
        int2 p0 = ep[e], p1 = ep[e + 1], p2 = ep[e + 2], p3 = ep[e + 3];
        float w0 = __int_as_float(p0.y), w1 = __int_as_float(p1.y);
        float w2 = __int_as_float(p2.y), w3 = __int_as_float(p3.y);
        uint2 q0 = *reinterpret_cast<const uint2*>(in + (size_t)p0.x * C + cc);
        uint2 q1 = *reinterpret_cast<const uint2*>(in + (size_t)p1.x * C + cc);
        uint2 q2 = *reinterpret_cast<const uint2*>(in + (size_t)p2.x * C + cc);
        uint2 q3 = *reinterpret_cast<const uint2*>(in + (size_t)p3.x * C + cc);
        float4 v0 = unpack_bf4(q0), v1 = unpack_bf4(q1);
        float4 v2 = unpack_bf4(q2), v3 = unpack_bf4(q3);
        a0.x += w0 * v0.x; a0.y += w0 * v0.y; a0.z += w0 * v0.z; a0.w += w0 * v0.w;
        a1.x += w1 * v1.x; a1.y += w1 * v1.y; a1.z += w1 * v1.z; a1.w += w1 * v1.w;
        a2.x += w2 * v2.x; a2.y += w2 * v2.y; a2.z += w2 * v2.z; a2.w += w2 * v2.w;
        a3.x += w3 * v3.x; a3.y += w3 * v3.y; a3.z += w3 * v3.z; a3.w += w3 * v3.w;
    }
    for (; e < end; ++e) {
        int2 p = ep[e];
        float w = __int_as_float(p.y);
        float4 v = unpack_bf4(*reinterpret_cast<const uint2*>(in + (size_t)p.x * C + cc));
        a0.x += w * v.x; a0.y += w * v.y; a0.z += w * v.z; a0.w += w * v.w;
    }
    float4 r = make_float4(a0.x + a1.x + a2.x + a3.x, a0.y + a1.y + a2.y + a3.y,
                           a0.z + a1.z + a2.z + a3.z, a0.w + a1.w + a2.w + a3.w);
    if constexpr (HASADD) {
        float4 ad = unpack_bf4(*reinterpret_cast<const uint2*>(addv + (size_t)node * C + cc));
        r.x += ad.x; r.y += ad.y; r.z += ad.z; r.w += ad.w;
    }
    if constexpr (RELU) {
        r.x = fmaxf(r.x, 0.f); r.y = fmaxf(r.y, 0.f);
        r.z = fmaxf(r.z, 0.f); r.w = fmaxf(r.w, 0.f);
    }
    *reinterpret_cast<uint2*>(out + (size_t)node * C + cc) =
        make_uint2(pack_bf(r.x, r.y), pack_bf(r.z, r.w));
}

// GCN agg + self-loop + bias + split-store, fused final stage (fp32 yh for precision).
__global__ void agg_gcn_final_kernel(const float* __restrict__ yh,
                                     const int* __restrict__ off,
                                     const int2* __restrict__ ep,
                                     const float* __restrict__ dis2,
                                     const float* __restrict__ bmu,
                                     const float* __restrict__ bls,
                                     float* __restrict__ outp, int n) {
    int t = blockIdx.x * blockDim.x + threadIdx.x;
    if (t >= n * 8) return;
    int node = t >> 3;
    int cc = (t & 7) * 4;
    int beg = off[node], end = off[node + 1];
    float4 a0 = make_float4(0.f, 0.f, 0.f, 0.f);
    float4 a1 = a0;
    int e = beg;
    for (; e + 2 <= end; e += 2) {
        int s0 = ep[e].x, s1 = ep[e + 1].x;
        float w0 = dis2[s0], w1 = dis2[s1];
        float4 v0 = *reinterpret_cast<const float4*>(yh + (size_t)s0 * 32 + cc);
        float4 v1 = *reinterpret_cast<const float4*>(yh + (size_t)s1 * 32 + cc);
        a0.x += w0 * v0.x; a0.y += w0 * v0.y; a0.z += w0 * v0.z; a0.w += w0 * v0.w;
        a1.x += w1 * v1.x; a1.y += w1 * v1.y; a1.z += w1 * v1.z; a1.w += w1 * v1.w;
    }
    for (; e < end; ++e) {
        int s = ep[e].x;
        float w = dis2[s];
        float4 v = *reinterpret_cast<const float4*>(yh + (size_t)s * 32 + cc);
        a0.x += w * v.x; a0.y += w * v.y; a0.z += w * v.z; a0.w += w * v.w;
    }
    float d = dis2[node];
    float4 yv = *reinterpret_cast<const float4*>(yh + (size_t)node * 32 + cc);
    const float* bp = (cc < 16) ? (bmu + cc) : (bls + cc - 16);
    float4 r;
    r.x = d * (a0.x + a1.x) + d * d * yv.x + bp[0];
    r.y = d * (a0.y + a1.y) + d * d * yv.y + bp[1];
    r.z = d * (a0.z + a1.z) + d * d * yv.z + bp[2];
    r.w = d * (a0.w + a1.w) + d * d * yv.w + bp[3];
    size_t o = (cc < 16) ? ((size_t)node * 16 + cc)
                         : ((size_t)n * 16 + (size_t)node * 16 + (cc - 16));
    *reinterpret_cast<float4*>(outp + o) = r;
}

// ----------------------------------------------------------------- matmul
__device__ __forceinline__ void fma4(float4& a, float s, const float4& w) {
    a.x += s * w.x; a.y += s * w.y; a.z += s * w.z; a.w += s * w.w;
}

// Fused multi-W matmul, bf16 weights staged in LDS (thrash-immune, ~6cyc reads).
// bf16 halves the round-6 LDS footprint: NW=2 L1 images = 27.6 KB -> 5 blocks/CU.
// out_w[n0..n0+1, c0..c0+3] = X[n0..n0+1, :] @ W_w (+bias on w=0).
// XBF: X rows are bf16 (stride KR elems); OBF: outputs stored bf16.
template <int KR, int PC, int NW, bool XBF, bool OBF, bool BIAS>
__global__ void mml_kernel(const void* __restrict__ Xv, const unsigned int* __restrict__ Wp,
                           const float* __restrict__ bp,
                           void* __restrict__ o0v, void* __restrict__ o1v, int n) {
    constexpr int CP4 = PC / 4;
    constexpr int PCU = PC / 2;
    constexpr int WU = NW * KR * PCU;
    __shared__ __align__(16) unsigned int Wl[WU];
    __shared__ __align__(16) float bl[PC];
    // straight vectorized copy: global images are already in the LDS layout
    {
        const uint4* s4 = reinterpret_cast<const uint4*>(Wp);
        uint4* d4 = reinterpret_cast<uint4*>(Wl);
        for (int i = threadIdx.x; i < WU / 4; i += blockDim.x) d4[i] = s4[i];
        if constexpr (BIAS)
            for (int i = threadIdx.x; i < PC; i += blockDim.x) bl[i] = bp[i];
    }
    __syncthreads();
    int idx = blockIdx.x * blockDim.x + threadIdx.x;
    if (idx >= (n >> 1) * CP4) return;
    int pair = idx / CP4;
    int c0 = (idx - pair * CP4) * 4;
    int n0 = pair * 2;
    const float* xaf = (const float*)Xv + (size_t)n0 * KR;
    const float* xbf = xaf + KR;
    const unsigned short* xah = (const unsigned short*)Xv + (size_t)n0 * KR;
    const unsigned short* xbh = xah + KR;
    const unsigned int* wc = Wl + (c0 >> 1);
    float4 acc[2][NW];
    #pragma unroll
    for (int w = 0; w < NW; ++w) {
        acc[0][w] = make_float4(0.f, 0.f, 0.f, 0.f);
        acc[1][w] = acc[0][w];
    }
    if constexpr (BIAS) {
        acc[0][0] = *reinterpret_cast<const float4*>(&bl[c0]);
        acc[1][0] = acc[0][0];
    }
    #pragma unroll 2
    for (int k4 = 0; k4 < KR / 4; ++k4) {
        float4 va, vb;
        if constexpr (XBF) {
            va = unpack_bf4(*reinterpret_cast<const uint2*>(xah + k4 * 4));
            vb = unpack_bf4(*reinterpret_cast<const uint2*>(xbh + k4 * 4));
        } else {
            va = *reinterpret_cast<const float4*>(xaf + k4 * 4);
            vb = *reinterpret_cast<const float4*>(xbf + k4 * 4);
        }
        #pragma unroll
        for (int j = 0; j < 4; ++j) {
            int k = k4 * 4 + j;
            float sa = (&va.x)[j];
            float sb = (&vb.x)[j];
            #pragma unroll
            for (int w = 0; w < NW; ++w) {
                uint2 q = *reinterpret_cast<const uint2*>(wc + (size_t)(w * KR + k) * PCU);
                float4 wv = unpack_bf4(q);
                fma4(acc[0][w], sa, wv);
                fma4(acc[1][w], sb, wv);
            }
        }
    }
    void* outs[2] = {o0v, o1v};
    #pragma unroll
    for (int w = 0; w < NW; ++w) {
        if constexpr (OBF) {
            unsigned short* o = (unsigned short*)outs[w] + (size_t)n0 * PC + c0;
            *reinterpret_cast<uint2*>(o) =
                make_uint2(pack_bf(acc[0][w].x, acc[0][w].y), pack_bf(acc[0][w].z, acc[0][w].w));
            *reinterpret_cast<uint2*>(o + PC) =
                make_uint2(pack_bf(acc[1][w].x, acc[1][w].y), pack_bf(acc[1][w].z, acc[1][w].w));
        } else {
            float* o = (float*)outs[w] + (size_t)n0 * PC + c0;
            *reinterpret_cast<float4*>(o) = acc[0][w];
            *reinterpret_cast<float4*>(o + PC) = acc[1][w];
        }
    }
}

// ------------------------------------------------------------------ launch

extern "C" void kernel_launch(void* const* d_in, const int* in_sizes, int n_in,
                              void* d_out, int out_size, void* d_ws, size_t ws_size,
                              hipStream_t stream) {
    const float* x   = (const float*)d_in[0];
    const int*   ei  = (const int*)d_in[1];
    const float* W1  = (const float*)d_in[2];
    const float* b1  = (const float*)d_in[3];
    const float* W2  = (const float*)d_in[4];
    const float* b2  = (const float*)d_in[5];
    const float* Wmu = (const float*)d_in[6];
    const float* bmu = (const float*)d_in[7];
    const float* Wls = (const float*)d_in[8];
    const float* bls = (const float*)d_in[9];
    float* out = (float*)d_out;

    const int N = NN, E = EE;
    const int* row = ei;
    const int* col = ei + E;

    // workspace carve-up (256B aligned)
    char* p = (char*)d_ws;
    auto alloc = [&](size_t bytes) -> char* {
        char* r = p;
        p += (bytes + 255) & ~(size_t)255;
        return r;
    };
    int*   deg    = (int*)alloc((size_t)N * 4);
    int*   off    = (int*)alloc((size_t)(N + 1) * 4);
    int*   cursor = (int*)alloc((size_t)N * 4);
    int*   bsum   = (int*)alloc((size_t)256 * 4);
    float* dis    = (float*)alloc((size_t)N * 4);
    float* dis2   = (float*)alloc((size_t)N * 4);
    unsigned int* wB = (unsigned int*)alloc((size_t)TUW * 4);
    float* bB     = (float*)alloc((size_t)NBF * 4);
    int2*  eTag   = (int2*)alloc((size_t)E * 8);
    unsigned short* y0 = (unsigned short*)alloc((size_t)N * S1 * 2);
    unsigned short* y1 = (unsigned short*)alloc((size_t)N * S1 * 2);
    unsigned short* y2 = (unsigned short*)alloc((size_t)N * S1 * 2);
    unsigned short* y3 = (unsigned short*)alloc((size_t)N * S1 * 2);
    unsigned short* u0 = (unsigned short*)alloc((size_t)N * S2 * 2);
    unsigned short* u1 = (unsigned short*)alloc((size_t)N * S2 * 2);
    unsigned short* u2 = (unsigned short*)alloc((size_t)N * S2 * 2);
    unsigned short* u3 = (unsigned short*)alloc((size_t)N * S2 * 2);
    float* yh     = (float*)alloc((size_t)N * 32 * 4);

    const unsigned int* W1b = wB;
    const unsigned int* W2b = wB + NU1;
    const unsigned int* Whb = wB + NU1 + NU2;
    const float* b1p = bB;
    const float* b2p = bB + S1;

    const int B = 256;
    int gE = (E + B - 1) / B;
    int nb = (N + SB - 1) / SB;  // 196 scan blocks

    // --- graph preprocessing -> CSR by destination (+ weight repack to bf16)
    hipMemsetAsync(deg, 0, (size_t)N * 4, stream);
    wpad_kernel<<<(TUW + NBF + B - 1) / B, B, 0, stream>>>(W1, b1, W2, b2, Wmu, Wls, wB, bB);
    hist_kernel<<<gE, B, 0, stream>>>(col, deg, E);
    reduce_kernel<<<nb, SB, 0, stream>>>(deg, bsum, N);
    scan_sums_kernel<<<1, SB, 0, stream>>>(bsum, nb);
    block_scan_kernel<<<nb, SB, 0, stream>>>(deg, bsum, off, cursor, dis, dis2, N);
    fill_kernel<<<gE, B, 0, stream>>>(row, col, dis, cursor, eTag, E);

    // grids
    int gm1 = ((N / 2) * (S1 / 4) + B - 1) / B;  // 1758
    int gm2 = ((N / 2) * (S2 / 4) + B - 1) / B;  // 1075
    int gmh = ((N / 2) * 8 + B - 1) / B;         // 782
    int ga72 = (N * (S1 / 4) + B - 1) / B;
    int ga44 = (N * (S2 / 4) + B - 1) / B;
    int ga32 = (N * 8 + B - 1) / B;

    // --- TAG layer 1 via Horner: o1 = relu(y0 + A(y1 + A(y2 + A*y3)))
    mml_kernel<CIN, S1, 2, false, true, true ><<<gm1, B, 0, stream>>>(x, W1b,             b1p, y0, y1, N);
    mml_kernel<CIN, S1, 2, false, true, false><<<gm1, B, 0, stream>>>(x, W1b + 2 * IMG1U, nullptr, y2, y3, N);
    aggb_kernel<S1, true, false><<<ga72, B, 0, stream>>>(y3, y2, y2, off, eTag, N);
    aggb_kernel<S1, true, false><<<ga72, B, 0, stream>>>(y2, y1, y1, off, eTag, N);
    aggb_kernel<S1, true, true ><<<ga72, B, 0, stream>>>(y1, y0, y0, off, eTag, N);
    // o1 = y0 (bf16, stride S1, pad cols zero)

    // --- TAG layer 2 via Horner: o2 = relu(u0 + A(u1 + A(u2 + A*u3)))
    mml_kernel<S1, S2, 2, true, true, true ><<<gm2, B, 0, stream>>>(y0, W2b,             b2p, u0, u1, N);
    mml_kernel<S1, S2, 2, true, true, false><<<gm2, B, 0, stream>>>(y0, W2b + 2 * IMG2U, nullptr, u2, u3, N);
    aggb_kernel<S2, true, false><<<ga44, B, 0, stream>>>(u3, u2, u2, off, eTag, N);
    aggb_kernel<S2, true, false><<<ga44, B, 0, stream>>>(u2, u1, u1, off, eTag, N);
    aggb_kernel<S2, true, true ><<<ga44, B, 0, stream>>>(u1, u0, u0, off, eTag, N);
    // o2 = u0 (bf16, stride S2, pad col zero)

    // --- GCN heads: head matmul (bf16 in LDS, fp32 out), then fused final agg
    mml_kernel<S2, 32, 1, true, false, false><<<gmh, B, 0, stream>>>(u0, Whb, nullptr, yh, nullptr, N);
    agg_gcn_final_kernel<<<ga32, B, 0, stream>>>(yh, off, eTag, dis2, bmu, bls, out, N);
}

// Round 10
// 408.117 us; speedup vs baseline: 1.4594x; 1.0377x over previous
//
#include <hip/hip_runtime.h>
#include <hip/hip_fp16.h>

// Problem constants (fixed by the reference)
static constexpr int NN  = 50000;   // nodes (even, < 65536 so src fits u16)
static constexpr int EE  = 800000;  // edges
static constexpr int CIN = 96;      // input channels
static constexpr int L1C = 70, S1 = 72;  // TAG layer 1 out, padded stride
static constexpr int L2C = 43, S2 = 44;  // TAG layer 2 out, padded stride

// bf16 weight image sizes (in uints = 2 bf16)
static constexpr int IMG1U = CIN * S1 / 2;   // 3456
static constexpr int IMG2U = S1 * S2 / 2;    // 1584
static constexpr int IMGHU = S2 * 32 / 2;    // 704
static constexpr int NU1 = 4 * IMG1U;        // 13824
static constexpr int NU2 = 4 * IMG2U;        // 6336
static constexpr int TUW = NU1 + NU2 + IMGHU; // 20864 uints
static constexpr int NBF = S1 + S2;          // bias floats (72 + 44)

// ------------------------------------------------------------ bf16 helpers
__device__ __forceinline__ float bf_lo(unsigned int u) {
    return __uint_as_float(u << 16);
}
__device__ __forceinline__ float bf_hi(unsigned int u) {
    return __uint_as_float(u & 0xffff0000u);
}
__device__ __forceinline__ unsigned int bf_rne_bits(float f) {
    unsigned int u = __float_as_uint(f);
    return u + 0x7fffu + ((u >> 16) & 1u);
}
__device__ __forceinline__ unsigned int pack_bf(float a, float b) {
    return (bf_rne_bits(a) >> 16) | (bf_rne_bits(b) & 0xffff0000u);
}
__device__ __forceinline__ float4 unpack_bf4(uint2 q) {
    return make_float4(bf_lo(q.x), bf_hi(q.x), bf_lo(q.y), bf_hi(q.y));
}

// edge record: src (low 16) | fp16 weight (high 16)
__device__ __forceinline__ int rec_src(unsigned int p) { return (int)(p & 0xffffu); }
__device__ __forceinline__ float rec_w(unsigned int p) {
    return __half2float(__ushort_as_half((unsigned short)(p >> 16)));
}

// ---------------------------------------------------------------- preprocessing

__global__ void hist_kernel(const int* __restrict__ col, int* __restrict__ deg, int E) {
    int e = blockIdx.x * blockDim.x + threadIdx.x;
    if (e < E) atomicAdd(&deg[col[e]], 1);
}

static constexpr int SB = 256;  // scan block size

__global__ void reduce_kernel(const int* __restrict__ deg, int* __restrict__ bsum, int n) {
    __shared__ int sd[SB];
    int i = blockIdx.x * SB + threadIdx.x;
    sd[threadIdx.x] = (i < n) ? deg[i] : 0;
    __syncthreads();
    for (int s = SB / 2; s > 0; s >>= 1) {
        if (threadIdx.x < s) sd[threadIdx.x] += sd[threadIdx.x + s];
        __syncthreads();
    }
    if (threadIdx.x == 0) bsum[blockIdx.x] = sd[0];
}

__global__ void scan_sums_kernel(int* __restrict__ bsum, int nb) {
    __shared__ int sd[SB];
    int v = (threadIdx.x < nb) ? bsum[threadIdx.x] : 0;
    sd[threadIdx.x] = v;
    __syncthreads();
    for (int s = 1; s < SB; s <<= 1) {
        int t = (threadIdx.x >= s) ? sd[threadIdx.x - s] : 0;
        __syncthreads();
        sd[threadIdx.x] += t;
        __syncthreads();
    }
    if (threadIdx.x < nb) bsum[threadIdx.x] = sd[threadIdx.x] - v;  // exclusive
}

__global__ void block_scan_kernel(const int* __restrict__ deg, const int* __restrict__ bsum,
                                  int* __restrict__ off, int* __restrict__ cursor,
                                  float* __restrict__ dis, float* __restrict__ dis2, int n) {
    __shared__ int sd[SB];
    int i = blockIdx.x * SB + threadIdx.x;
    int v = (i < n) ? deg[i] : 0;
    sd[threadIdx.x] = v;
    __syncthreads();
    for (int s = 1; s < SB; s <<= 1) {
        int t = (threadIdx.x >= s) ? sd[threadIdx.x - s] : 0;
        __syncthreads();
        sd[threadIdx.x] += t;
        __syncthreads();
    }
    if (i < n) {
        int e = bsum[blockIdx.x] + sd[threadIdx.x] - v;
        off[i] = e;
        cursor[i] = e;
        dis[i]  = (v > 0) ? rsqrtf((float)v) : 0.0f;
        dis2[i] = rsqrtf((float)v + 1.0f);
        if (i == n - 1) off[n] = e + v;
    }
}

// pack (src, fp16 TAG weight) into 4B records; nontemporal scatter (no
// write-allocate -> no cross-XCD line bounce; r9: 8B cached scatter wrote 52MB).
__global__ void fill_kernel(const int* __restrict__ row, const int* __restrict__ col,
                            const float* __restrict__ dis, int* __restrict__ cursor,
                            unsigned int* __restrict__ eTag, int E) {
    int e = blockIdx.x * blockDim.x + threadIdx.x;
    if (e < E) {
        int r = row[e], c = col[e];
        int pos = atomicAdd(&cursor[c], 1);
        unsigned short h = __half_as_ushort(__float2half(dis[r] * dis[c]));
        unsigned int rec = (unsigned int)r | ((unsigned int)h << 16);
        __builtin_nontemporal_store(rec, &eTag[pos]);
    }
}

// repack weights into padded bf16 global images + padded fp32 biases
__global__ void wpad_kernel(const float* __restrict__ W1, const float* __restrict__ b1,
                            const float* __restrict__ W2, const float* __restrict__ b2,
                            const float* __restrict__ Wmu, const float* __restrict__ Wls,
                            unsigned int* __restrict__ wB, float* __restrict__ bB) {
    int i = blockIdx.x * blockDim.x + threadIdx.x;
    if (i < TUW) {
        float v0 = 0.f, v1 = 0.f;
        if (i < NU1) {
            int img = i / IMG1U, r = i - img * IMG1U;
            int k = r / (S1 / 2), c0 = (r - k * (S1 / 2)) * 2;
            const float* Wi = W1 + (size_t)img * CIN * L1C + (size_t)k * L1C;
            if (c0 < L1C) v0 = Wi[c0];
            if (c0 + 1 < L1C) v1 = Wi[c0 + 1];
        } else if (i < NU1 + NU2) {
            int j = i - NU1;
            int img = j / IMG2U, r = j - img * IMG2U;
            int k = r / (S2 / 2), c0 = (r - k * (S2 / 2)) * 2;
            if (k < L1C) {
                const float* Wi = W2 + (size_t)img * L1C * L2C + (size_t)k * L2C;
                if (c0 < L2C) v0 = Wi[c0];
                if (c0 + 1 < L2C) v1 = Wi[c0 + 1];
            }
        } else {
            int j = i - NU1 - NU2;
            int k = j / 16, c0 = (j - k * 16) * 2;  // 32 cols -> 16 uints per row
            if (k < L2C) {
                v0 = (c0 < 16) ? Wmu[k * 16 + c0] : Wls[k * 16 + (c0 - 16)];
                int c1 = c0 + 1;
                v1 = (c1 < 16) ? Wmu[k * 16 + c1] : Wls[k * 16 + (c1 - 16)];
            }
        }
        wB[i] = pack_bf(v0, v1);
    } else if (i < TUW + NBF) {
        int j = i - TUW;
        float v = 0.f;
        if (j < S1) { if (j < L1C) v = b1[j]; }
        else { int k = j - S1; if (k < L2C) v = b2[k]; }
        bB[j] = v;
    }
}

// ------------------------------------------------------------- aggregation (bf16)
// out[i][:] = (HASADD ? addv[i][:] : 0) + sum_e w_e * in[src_e][:]  (+ ReLU)
// bf16 storage, fp32 accumulate, 4B edge records. In-place safe for out==addv.
template <int C, bool HASADD, bool RELU>
__global__ void aggb_kernel(const unsigned short* __restrict__ in, const unsigned short* addv,
                            unsigned short* out, const int* __restrict__ off,
                            const unsigned int* __restrict__ ep, int n) {
    constexpr int TPN = C / 4;  // threads per node (4 bf16 channels each)
    int t = blockIdx.x * blockDim.x + threadIdx.x;
    if (t >= n * TPN) return;
    int node = t / TPN;
    int cc = (t - node * TPN) * 4;
    int beg = off[node], end = off[node + 1];
    float4 a0 = make_float4(0.f, 0.f, 0.f, 0.f);
    float4 a1 = a0, a2 = a0, a3 = a0;
    int e = beg;
    for (; e + 4 <= end; e += 4) {
        unsigned int p0 = ep[e], p1 = ep[e + 1], p2 = ep[e + 2], p3 = ep[e + 3];
        float w0 = rec_w(p0), w1 = rec_w(p1), w2 = rec_w(p2), w3 = rec_w(p3);
        uint2 q0 = *reinterpret_cast<const uint2*>(in + (size_t)rec_src(p0) * C + cc);
        uint2 q1 = *reinterpret_cast<const uint2*>(in + (size_t)rec_src(p1) * C + cc);
        uint2 q2 = *reinterpret_cast<const uint2*>(in + (size_t)rec_src(p2) * C + cc);
        uint2 q3 = *reinterpret_cast<const uint2*>(in + (size_t)rec_src(p3) * C + cc);
        float4 v0 = unpack_bf4(q0), v1 = unpack_bf4(q1);
        float4 v2 = unpack_bf4(q2), v3 = unpack_bf4(q3);
        a0.x += w0 * v0.x; a0.y += w0 * v0.y; a0.z += w0 * v0.z; a0.w += w0 * v0.w;
        a1.x += w1 * v1.x; a1.y += w1 * v1.y; a1.z += w1 * v1.z; a1.w += w1 * v1.w;
        a2.x += w2 * v2.x; a2.y += w2 * v2.y; a2.z += w2 * v2.z; a2.w += w2 * v2.w;
        a3.x += w3 * v3.x; a3.y += w3 * v3.y; a3.z += w3 * v3.z; a3.w += w3 * v3.w;
    }
    for (; e < end; ++e) {
        unsigned int p = ep[e];
        float w = rec_w(p);
        float4 v = unpack_bf4(*reinterpret_cast<const uint2*>(in + (size_t)rec_src(p) * C + cc));
        a0.x += w * v.x; a0.y += w * v.y; a0.z += w * v.z; a0.w += w * v.w;
    }
    float4 r = make_float4(a0.x + a1.x + a2.x + a3.x, a0.y + a1.y + a2.y + a3.y,
                           a0.z + a1.z + a2.z + a3.z, a0.w + a1.w + a2.w + a3.w);
    if constexpr (HASADD) {
        float4 ad = unpack_bf4(*reinterpret_cast<const uint2*>(addv + (size_t)node * C + cc));
        r.x += ad.x; r.y += ad.y; r.z += ad.z; r.w += ad.w;
    }
    if constexpr (RELU) {
        r.x = fmaxf(r.x, 0.f); r.y = fmaxf(r.y, 0.f);
        r.z = fmaxf(r.z, 0.f); r.w = fmaxf(r.w, 0.f);
    }
    *reinterpret_cast<uint2*>(out + (size_t)node * C + cc) =
        make_uint2(pack_bf(r.x, r.y), pack_bf(r.z, r.w));
}

// GCN agg + self-loop + bias + split-store, fused final stage. yh is bf16 (halves
// the 102MB gather); GCN edge weight recomputed from L2-resident dis2 table.
__global__ void agg_gcn_final_kernel(const unsigned short* __restrict__ yh,
                                     const int* __restrict__ off,
                                     const unsigned int* __restrict__ ep,
                                     const float* __restrict__ dis2,
                                     const float* __restrict__ bmu,
                                     const float* __restrict__ bls,
                                     float* __restrict__ outp, int n) {
    int t = blockIdx.x * blockDim.x + threadIdx.x;
    if (t >= n * 8) return;
    int node = t >> 3;
    int cc = (t & 7) * 4;
    int beg = off[node], end = off[node + 1];
    float4 a0 = make_float4(0.f, 0.f, 0.f, 0.f);
    float4 a1 = a0;
    int e = beg;
    for (; e + 2 <= end; e += 2) {
        int s0 = rec_src(ep[e]), s1 = rec_src(ep[e + 1]);
        float w0 = dis2[s0], w1 = dis2[s1];
        float4 v0 = unpack_bf4(*reinterpret_cast<const uint2*>(yh + (size_t)s0 * 32 + cc));
        float4 v1 = unpack_bf4(*reinterpret_cast<const uint2*>(yh + (size_t)s1 * 32 + cc));
        a0.x += w0 * v0.x; a0.y += w0 * v0.y; a0.z += w0 * v0.z; a0.w += w0 * v0.w;
        a1.x += w1 * v1.x; a1.y += w1 * v1.y; a1.z += w1 * v1.z; a1.w += w1 * v1.w;
    }
    for (; e < end; ++e) {
        int s = rec_src(ep[e]);
        float w = dis2[s];
        float4 v = unpack_bf4(*reinterpret_cast<const uint2*>(yh + (size_t)s * 32 + cc));
        a0.x += w * v.x; a0.y += w * v.y; a0.z += w * v.z; a0.w += w * v.w;
    }
    float d = dis2[node];
    float4 yv = unpack_bf4(*reinterpret_cast<const uint2*>(yh + (size_t)node * 32 + cc));
    const float* bp = (cc < 16) ? (bmu + cc) : (bls + cc - 16);
    float4 r;
    r.x = d * (a0.x + a1.x) + d * d * yv.x + bp[0];
    r.y = d * (a0.y + a1.y) + d * d * yv.y + bp[1];
    r.z = d * (a0.z + a1.z) + d * d * yv.z + bp[2];
    r.w = d * (a0.w + a1.w) + d * d * yv.w + bp[3];
    size_t o = (cc < 16) ? ((size_t)node * 16 + cc)
                         : ((size_t)n * 16 + (size_t)node * 16 + (cc - 16));
    *reinterpret_cast<float4*>(outp + o) = r;
}

// ----------------------------------------------------------------- matmul
__device__ __forceinline__ void fma4(float4& a, float s, const float4& w) {
    a.x += s * w.x; a.y += s * w.y; a.z += s * w.z; a.w += s * w.w;
}

// Fused multi-W matmul, bf16 weights staged in LDS (thrash-immune, ~6cyc reads).
// out_w[n0..n0+1, c0..c0+3] = X[n0..n0+1, :] @ W_w (+bias on w=0).
// XBF: X rows are bf16 (stride KR elems); OBF: outputs stored bf16.
template <int KR, int PC, int NW, bool XBF, bool OBF, bool BIAS>
__global__ void mml_kernel(const void* __restrict__ Xv, const unsigned int* __restrict__ Wp,
                           const float* __restrict__ bp,
                           void* __restrict__ o0v, void* __restrict__ o1v, int n) {
    constexpr int CP4 = PC / 4;
    constexpr int PCU = PC / 2;
    constexpr int WU = NW * KR * PCU;
    __shared__ __align__(16) unsigned int Wl[WU];
    __shared__ __align__(16) float bl[PC];
    // straight vectorized copy: global images are already in the LDS layout
    {
        const uint4* s4 = reinterpret_cast<const uint4*>(Wp);
        uint4* d4 = reinterpret_cast<uint4*>(Wl);
        for (int i = threadIdx.x; i < WU / 4; i += blockDim.x) d4[i] = s4[i];
        if constexpr (BIAS)
            for (int i = threadIdx.x; i < PC; i += blockDim.x) bl[i] = bp[i];
    }
    __syncthreads();
    int idx = blockIdx.x * blockDim.x + threadIdx.x;
    if (idx >= (n >> 1) * CP4) return;
    int pair = idx / CP4;
    int c0 = (idx - pair * CP4) * 4;
    int n0 = pair * 2;
    const float* xaf = (const float*)Xv + (size_t)n0 * KR;
    const float* xbf = xaf + KR;
    const unsigned short* xah = (const unsigned short*)Xv + (size_t)n0 * KR;
    const unsigned short* xbh = xah + KR;
    const unsigned int* wc = Wl + (c0 >> 1);
    float4 acc[2][NW];
    #pragma unroll
    for (int w = 0; w < NW; ++w) {
        acc[0][w] = make_float4(0.f, 0.f, 0.f, 0.f);
        acc[1][w] = acc[0][w];
    }
    if constexpr (BIAS) {
        acc[0][0] = *reinterpret_cast<const float4*>(&bl[c0]);
        acc[1][0] = acc[0][0];
    }
    #pragma unroll 2
    for (int k4 = 0; k4 < KR / 4; ++k4) {
        float4 va, vb;
        if constexpr (XBF) {
            va = unpack_bf4(*reinterpret_cast<const uint2*>(xah + k4 * 4));
            vb = unpack_bf4(*reinterpret_cast<const uint2*>(xbh + k4 * 4));
        } else {
            va = *reinterpret_cast<const float4*>(xaf + k4 * 4);
            vb = *reinterpret_cast<const float4*>(xbf + k4 * 4);
        }
        #pragma unroll
        for (int j = 0; j < 4; ++j) {
            int k = k4 * 4 + j;
            float sa = (&va.x)[j];
            float sb = (&vb.x)[j];
            #pragma unroll
            for (int w = 0; w < NW; ++w) {
                uint2 q = *reinterpret_cast<const uint2*>(wc + (size_t)(w * KR + k) * PCU);
                float4 wv = unpack_bf4(q);
                fma4(acc[0][w], sa, wv);
                fma4(acc[1][w], sb, wv);
            }
        }
    }
    void* outs[2] = {o0v, o1v};
    #pragma unroll
    for (int w = 0; w < NW; ++w) {
        if constexpr (OBF) {
            unsigned short* o = (unsigned short*)outs[w] + (size_t)n0 * PC + c0;
            *reinterpret_cast<uint2*>(o) =
                make_uint2(pack_bf(acc[0][w].x, acc[0][w].y), pack_bf(acc[0][w].z, acc[0][w].w));
            *reinterpret_cast<uint2*>(o + PC) =
                make_uint2(pack_bf(acc[1][w].x, acc[1][w].y), pack_bf(acc[1][w].z, acc[1][w].w));
        } else {
            float* o = (float*)outs[w] + (size_t)n0 * PC + c0;
            *reinterpret_cast<float4*>(o) = acc[0][w];
            *reinterpret_cast<float4*>(o + PC) = acc[1][w];
        }
    }
}

// ------------------------------------------------------------------ launch

extern "C" void kernel_launch(void* const* d_in, const int* in_sizes, int n_in,
                              void* d_out, int out_size, void* d_ws, size_t ws_size,
                              hipStream_t stream) {
    const float* x   = (const float*)d_in[0];
    const int*   ei  = (const int*)d_in[1];
    const float* W1  = (const float*)d_in[2];
    const float* b1  = (const float*)d_in[3];
    const float* W2  = (const float*)d_in[4];
    const float* b2  = (const float*)d_in[5];
    const float* Wmu = (const float*)d_in[6];
    const float* bmu = (const float*)d_in[7];
    const float* Wls = (const float*)d_in[8];
    const float* bls = (const float*)d_in[9];
    float* out = (float*)d_out;

    const int N = NN, E = EE;
    const int* row = ei;
    const int* col = ei + E;

    // workspace carve-up (256B aligned)
    char* p = (char*)d_ws;
    auto alloc = [&](size_t bytes) -> char* {
        char* r = p;
        p += (bytes + 255) & ~(size_t)255;
        return r;
    };
    int*   deg    = (int*)alloc((size_t)N * 4);
    int*   off    = (int*)alloc((size_t)(N + 1) * 4);
    int*   cursor = (int*)alloc((size_t)N * 4);
    int*   bsum   = (int*)alloc((size_t)256 * 4);
    float* dis    = (float*)alloc((size_t)N * 4);
    float* dis2   = (float*)alloc((size_t)N * 4);
    unsigned int* wB = (unsigned int*)alloc((size_t)TUW * 4);
    float* bB     = (float*)alloc((size_t)NBF * 4);
    unsigned int* eTag = (unsigned int*)alloc((size_t)E * 4);
    unsigned short* y0 = (unsigned short*)alloc((size_t)N * S1 * 2);
    unsigned short* y1 = (unsigned short*)alloc((size_t)N * S1 * 2);
    unsigned short* y2 = (unsigned short*)alloc((size_t)N * S1 * 2);
    unsigned short* y3 = (unsigned short*)alloc((size_t)N * S1 * 2);
    unsigned short* u0 = (unsigned short*)alloc((size_t)N * S2 * 2);
    unsigned short* u1 = (unsigned short*)alloc((size_t)N * S2 * 2);
    unsigned short* u2 = (unsigned short*)alloc((size_t)N * S2 * 2);
    unsigned short* u3 = (unsigned short*)alloc((size_t)N * S2 * 2);
    unsigned short* yh = (unsigned short*)alloc((size_t)N * 32 * 2);

    const unsigned int* W1b = wB;
    const unsigned int* W2b = wB + NU1;
    const unsigned int* Whb = wB + NU1 + NU2;
    const float* b1p = bB;
    const float* b2p = bB + S1;

    const int B = 256;
    int gE = (E + B - 1) / B;
    int nb = (N + SB - 1) / SB;  // 196 scan blocks

    // --- graph preprocessing -> CSR by destination (+ weight repack to bf16)
    hipMemsetAsync(deg, 0, (size_t)N * 4, stream);
    wpad_kernel<<<(TUW + NBF + B - 1) / B, B, 0, stream>>>(W1, b1, W2, b2, Wmu, Wls, wB, bB);
    hist_kernel<<<gE, B, 0, stream>>>(col, deg, E);
    reduce_kernel<<<nb, SB, 0, stream>>>(deg, bsum, N);
    scan_sums_kernel<<<1, SB, 0, stream>>>(bsum, nb);
    block_scan_kernel<<<nb, SB, 0, stream>>>(deg, bsum, off, cursor, dis, dis2, N);
    fill_kernel<<<gE, B, 0, stream>>>(row, col, dis, cursor, eTag, E);

    // grids
    int gm1 = ((N / 2) * (S1 / 4) + B - 1) / B;  // 1758
    int gm2 = ((N / 2) * (S2 / 4) + B - 1) / B;  // 1075
    int gmh = ((N / 2) * 8 + B - 1) / B;         // 782
    int ga72 = (N * (S1 / 4) + B - 1) / B;
    int ga44 = (N * (S2 / 4) + B - 1) / B;
    int ga32 = (N * 8 + B - 1) / B;

    // --- TAG layer 1 via Horner: o1 = relu(y0 + A(y1 + A(y2 + A*y3)))
    mml_kernel<CIN, S1, 2, false, true, true ><<<gm1, B, 0, stream>>>(x, W1b,             b1p, y0, y1, N);
    mml_kernel<CIN, S1, 2, false, true, false><<<gm1, B, 0, stream>>>(x, W1b + 2 * IMG1U, nullptr, y2, y3, N);
    aggb_kernel<S1, true, false><<<ga72, B, 0, stream>>>(y3, y2, y2, off, eTag, N);
    aggb_kernel<S1, true, false><<<ga72, B, 0, stream>>>(y2, y1, y1, off, eTag, N);
    aggb_kernel<S1, true, true ><<<ga72, B, 0, stream>>>(y1, y0, y0, off, eTag, N);
    // o1 = y0 (bf16, stride S1, pad cols zero)

    // --- TAG layer 2 via Horner: o2 = relu(u0 + A(u1 + A(u2 + A*u3)))
    mml_kernel<S1, S2, 2, true, true, true ><<<gm2, B, 0, stream>>>(y0, W2b,             b2p, u0, u1, N);
    mml_kernel<S1, S2, 2, true, true, false><<<gm2, B, 0, stream>>>(y0, W2b + 2 * IMG2U, nullptr, u2, u3, N);
    aggb_kernel<S2, true, false><<<ga44, B, 0, stream>>>(u3, u2, u2, off, eTag, N);
    aggb_kernel<S2, true, false><<<ga44, B, 0, stream>>>(u2, u1, u1, off, eTag, N);
    aggb_kernel<S2, true, true ><<<ga44, B, 0, stream>>>(u1, u0, u0, off, eTag, N);
    // o2 = u0 (bf16, stride S2, pad col zero)

    // --- GCN heads: head matmul (bf16 in LDS, bf16 out), then fused final agg
    mml_kernel<S2, 32, 1, true, true, false><<<gmh, B, 0, stream>>>(u0, Whb, nullptr, yh, nullptr, N);
    agg_gcn_final_kernel<<<ga32, B, 0, stream>>>(yh, off, eTag, dis2, bmu, bls, out, N);
}

// Round 11
// 393.449 us; speedup vs baseline: 1.5138x; 1.0373x over previous
//
#include <hip/hip_runtime.h>
#include <hip/hip_fp16.h>

// Problem constants (fixed by the reference)
static constexpr int NN  = 50000;   // nodes (even, < 65536 so src fits u16)
static constexpr int EE  = 800000;  // edges
static constexpr int CIN = 96;      // input channels
static constexpr int L1C = 70, S1 = 72;   // TAG layer 1 out, padded stride (9x16B)
static constexpr int L2C = 43, S2P = 48;  // TAG layer 2 out, padded stride (6x16B)

// bf16 weight image sizes (in uints = 2 bf16)
static constexpr int IMG1U = CIN * S1 / 2;    // 3456
static constexpr int IMG2U = S1 * S2P / 2;    // 1728
static constexpr int IMGHU = S2P * 32 / 2;    // 768
static constexpr int NU1 = 4 * IMG1U;         // 13824
static constexpr int NU2 = 4 * IMG2U;         // 6912
static constexpr int TUW = NU1 + NU2 + IMGHU; // 21504 uints
static constexpr int NBF = S1 + S2P;          // bias floats (72 + 48)

// ------------------------------------------------------------ bf16 helpers
__device__ __forceinline__ float bf_lo(unsigned int u) {
    return __uint_as_float(u << 16);
}
__device__ __forceinline__ float bf_hi(unsigned int u) {
    return __uint_as_float(u & 0xffff0000u);
}
__device__ __forceinline__ unsigned int bf_rne_bits(float f) {
    unsigned int u = __float_as_uint(f);
    return u + 0x7fffu + ((u >> 16) & 1u);
}
__device__ __forceinline__ unsigned int pack_bf(float a, float b) {
    return (bf_rne_bits(a) >> 16) | (bf_rne_bits(b) & 0xffff0000u);
}
__device__ __forceinline__ float4 unpack_bf4(uint2 q) {
    return make_float4(bf_lo(q.x), bf_hi(q.x), bf_lo(q.y), bf_hi(q.y));
}
__device__ __forceinline__ void unpack_bf8(uint4 q, float* f) {
    f[0] = bf_lo(q.x); f[1] = bf_hi(q.x); f[2] = bf_lo(q.y); f[3] = bf_hi(q.y);
    f[4] = bf_lo(q.z); f[5] = bf_hi(q.z); f[6] = bf_lo(q.w); f[7] = bf_hi(q.w);
}

// edge record: src (low 16) | fp16 weight (high 16)
__device__ __forceinline__ int rec_src(unsigned int p) { return (int)(p & 0xffffu); }
__device__ __forceinline__ float rec_w(unsigned int p) {
    return __half2float(__ushort_as_half((unsigned short)(p >> 16)));
}

// ---------------------------------------------------------------- preprocessing

__global__ void hist_kernel(const int* __restrict__ col, int* __restrict__ deg, int E) {
    int e = blockIdx.x * blockDim.x + threadIdx.x;
    if (e < E) atomicAdd(&deg[col[e]], 1);
}

static constexpr int SB = 256;  // scan block size

__global__ void reduce_kernel(const int* __restrict__ deg, int* __restrict__ bsum, int n) {
    __shared__ int sd[SB];
    int i = blockIdx.x * SB + threadIdx.x;
    sd[threadIdx.x] = (i < n) ? deg[i] : 0;
    __syncthreads();
    for (int s = SB / 2; s > 0; s >>= 1) {
        if (threadIdx.x < s) sd[threadIdx.x] += sd[threadIdx.x + s];
        __syncthreads();
    }
    if (threadIdx.x == 0) bsum[blockIdx.x] = sd[0];
}

__global__ void scan_sums_kernel(int* __restrict__ bsum, int nb) {
    __shared__ int sd[SB];
    int v = (threadIdx.x < nb) ? bsum[threadIdx.x] : 0;
    sd[threadIdx.x] = v;
    __syncthreads();
    for (int s = 1; s < SB; s <<= 1) {
        int t = (threadIdx.x >= s) ? sd[threadIdx.x - s] : 0;
        __syncthreads();
        sd[threadIdx.x] += t;
        __syncthreads();
    }
    if (threadIdx.x < nb) bsum[threadIdx.x] = sd[threadIdx.x] - v;  // exclusive
}

__global__ void block_scan_kernel(const int* __restrict__ deg, const int* __restrict__ bsum,
                                  int* __restrict__ off, int* __restrict__ cursor,
                                  float* __restrict__ dis, float* __restrict__ dis2, int n) {
    __shared__ int sd[SB];
    int i = blockIdx.x * SB + threadIdx.x;
    int v = (i < n) ? deg[i] : 0;
    sd[threadIdx.x] = v;
    __syncthreads();
    for (int s = 1; s < SB; s <<= 1) {
        int t = (threadIdx.x >= s) ? sd[threadIdx.x - s] : 0;
        __syncthreads();
        sd[threadIdx.x] += t;
        __syncthreads();
    }
    if (i < n) {
        int e = bsum[blockIdx.x] + sd[threadIdx.x] - v;
        off[i] = e;
        cursor[i] = e;
        dis[i]  = (v > 0) ? rsqrtf((float)v) : 0.0f;
        dis2[i] = rsqrtf((float)v + 1.0f);
        if (i == n - 1) off[n] = e + v;
    }
}

// pack (src, fp16 TAG weight) into 4B records. Plain cached stores: r10 showed
// nontemporal 4B scatter writes ~83B/record to HBM (no L2 merge) — cached lets
// 16 records/line coalesce in L2 before writeback.
__global__ void fill_kernel(const int* __restrict__ row, const int* __restrict__ col,
                            const float* __restrict__ dis, int* __restrict__ cursor,
                            unsigned int* __restrict__ eTag, int E) {
    int e = blockIdx.x * blockDim.x + threadIdx.x;
    if (e < E) {
        int r = row[e], c = col[e];
        int pos = atomicAdd(&cursor[c], 1);
        unsigned short h = __half_as_ushort(__float2half(dis[r] * dis[c]));
        eTag[pos] = (unsigned int)r | ((unsigned int)h << 16);
    }
}

// repack weights into padded bf16 global images + padded fp32 biases
__global__ void wpad_kernel(const float* __restrict__ W1, const float* __restrict__ b1,
                            const float* __restrict__ W2, const float* __restrict__ b2,
                            const float* __restrict__ Wmu, const float* __restrict__ Wls,
                            unsigned int* __restrict__ wB, float* __restrict__ bB) {
    int i = blockIdx.x * blockDim.x + threadIdx.x;
    if (i < TUW) {
        float v0 = 0.f, v1 = 0.f;
        if (i < NU1) {
            int img = i / IMG1U, r = i - img * IMG1U;
            int k = r / (S1 / 2), c0 = (r - k * (S1 / 2)) * 2;
            const float* Wi = W1 + (size_t)img * CIN * L1C + (size_t)k * L1C;
            if (c0 < L1C) v0 = Wi[c0];
            if (c0 + 1 < L1C) v1 = Wi[c0 + 1];
        } else if (i < NU1 + NU2) {
            int j = i - NU1;
            int img = j / IMG2U, r = j - img * IMG2U;
            int k = r / (S2P / 2), c0 = (r - k * (S2P / 2)) * 2;
            if (k < L1C) {
                const float* Wi = W2 + (size_t)img * L1C * L2C + (size_t)k * L2C;
                if (c0 < L2C) v0 = Wi[c0];
                if (c0 + 1 < L2C) v1 = Wi[c0 + 1];
            }
        } else {
            int j = i - NU1 - NU2;
            int k = j / 16, c0 = (j - k * 16) * 2;  // 32 cols -> 16 uints per row
            if (k < L2C) {
                v0 = (c0 < 16) ? Wmu[k * 16 + c0] : Wls[k * 16 + (c0 - 16)];
                int c1 = c0 + 1;
                v1 = (c1 < 16) ? Wmu[k * 16 + c1] : Wls[k * 16 + (c1 - 16)];
            }
        }
        wB[i] = pack_bf(v0, v1);
    } else if (i < TUW + NBF) {
        int j = i - TUW;
        float v = 0.f;
        if (j < S1) { if (j < L1C) v = b1[j]; }
        else { int k = j - S1; if (k < L2C) v = b2[k]; }
        bB[j] = v;
    }
}

// ------------------------------------------------------------- aggregation (bf16)
// Wide-gather variant: thread = (node, 8-channel group) -> one uint4 (16B) per
// edge gather, halving the L2 request count vs 8B (r10 aggs were request-bound).
// out[i][:] = (HASADD ? addv[i][:] : 0) + sum_e w_e * in[src_e][:]  (+ ReLU)
template <int C, bool HASADD, bool RELU>
__global__ void aggw_kernel(const unsigned short* __restrict__ in, const unsigned short* addv,
                            unsigned short* out, const int* __restrict__ off,
                            const unsigned int* __restrict__ ep, int n) {
    constexpr int TPN = C / 8;  // threads per node (8 bf16 channels each)
    int t = blockIdx.x * blockDim.x + threadIdx.x;
    if (t >= n * TPN) return;
    int node = t / TPN;
    int cc = (t - node * TPN) * 8;
    int beg = off[node], end = off[node + 1];
    float a0[8], a1[8];
    #pragma unroll
    for (int j = 0; j < 8; ++j) { a0[j] = 0.f; a1[j] = 0.f; }
    int e = beg;
    for (; e + 4 <= end; e += 4) {
        unsigned int p0 = ep[e], p1 = ep[e + 1], p2 = ep[e + 2], p3 = ep[e + 3];
        float w0 = rec_w(p0), w1 = rec_w(p1), w2 = rec_w(p2), w3 = rec_w(p3);
        uint4 q0 = *reinterpret_cast<const uint4*>(in + (size_t)rec_src(p0) * C + cc);
        uint4 q1 = *reinterpret_cast<const uint4*>(in + (size_t)rec_src(p1) * C + cc);
        uint4 q2 = *reinterpret_cast<const uint4*>(in + (size_t)rec_src(p2) * C + cc);
        uint4 q3 = *reinterpret_cast<const uint4*>(in + (size_t)rec_src(p3) * C + cc);
        float f[8];
        unpack_bf8(q0, f);
        #pragma unroll
        for (int j = 0; j < 8; ++j) a0[j] += w0 * f[j];
        unpack_bf8(q1, f);
        #pragma unroll
        for (int j = 0; j < 8; ++j) a1[j] += w1 * f[j];
        unpack_bf8(q2, f);
        #pragma unroll
        for (int j = 0; j < 8; ++j) a0[j] += w2 * f[j];
        unpack_bf8(q3, f);
        #pragma unroll
        for (int j = 0; j < 8; ++j) a1[j] += w3 * f[j];
    }
    for (; e < end; ++e) {
        unsigned int p = ep[e];
        float w = rec_w(p);
        uint4 q = *reinterpret_cast<const uint4*>(in + (size_t)rec_src(p) * C + cc);
        float f[8];
        unpack_bf8(q, f);
        #pragma unroll
        for (int j = 0; j < 8; ++j) a0[j] += w * f[j];
    }
    float r[8];
    #pragma unroll
    for (int j = 0; j < 8; ++j) r[j] = a0[j] + a1[j];
    if constexpr (HASADD) {
        uint4 qa = *reinterpret_cast<const uint4*>(addv + (size_t)node * C + cc);
        float f[8];
        unpack_bf8(qa, f);
        #pragma unroll
        for (int j = 0; j < 8; ++j) r[j] += f[j];
    }
    if constexpr (RELU) {
        #pragma unroll
        for (int j = 0; j < 8; ++j) r[j] = fmaxf(r[j], 0.f);
    }
    uint4 o;
    o.x = pack_bf(r[0], r[1]); o.y = pack_bf(r[2], r[3]);
    o.z = pack_bf(r[4], r[5]); o.w = pack_bf(r[6], r[7]);
    *reinterpret_cast<uint4*>(out + (size_t)node * C + cc) = o;
}

// GCN agg + self-loop + bias + split-store, fused final stage. bf16 yh, 16B
// gathers (4 threads/node x 8 channels); GCN edge weight from dis2 table.
__global__ void agg_gcn_final_kernel(const unsigned short* __restrict__ yh,
                                     const int* __restrict__ off,
                                     const unsigned int* __restrict__ ep,
                                     const float* __restrict__ dis2,
                                     const float* __restrict__ bmu,
                                     const float* __restrict__ bls,
                                     float* __restrict__ outp, int n) {
    int t = blockIdx.x * blockDim.x + threadIdx.x;
    if (t >= n * 4) return;
    int node = t >> 2;
    int cc = (t & 3) * 8;
    int beg = off[node], end = off[node + 1];
    float a0[8], a1[8];
    #pragma unroll
    for (int j = 0; j < 8; ++j) { a0[j] = 0.f; a1[j] = 0.f; }
    int e = beg;
    for (; e + 2 <= end; e += 2) {
        int s0 = rec_src(ep[e]), s1 = rec_src(ep[e + 1]);
        float w0 = dis2[s0], w1 = dis2[s1];
        uint4 q0 = *reinterpret_cast<const uint4*>(yh + (size_t)s0 * 32 + cc);
        uint4 q1 = *reinterpret_cast<const uint4*>(yh + (size_t)s1 * 32 + cc);
        float f[8];
        unpack_bf8(q0, f);
        #pragma unroll
        for (int j = 0; j < 8; ++j) a0[j] += w0 * f[j];
        unpack_bf8(q1, f);
        #pragma unroll
        for (int j = 0; j < 8; ++j) a1[j] += w1 * f[j];
    }
    for (; e < end; ++e) {
        int s = rec_src(ep[e]);
        float w = dis2[s];
        uint4 q = *reinterpret_cast<const uint4*>(yh + (size_t)s * 32 + cc);
        float f[8];
        unpack_bf8(q, f);
        #pragma unroll
        for (int j = 0; j < 8; ++j) a0[j] += w * f[j];
    }
    float d = dis2[node];
    uint4 qy = *reinterpret_cast<const uint4*>(yh + (size_t)node * 32 + cc);
    float yv[8];
    unpack_bf8(qy, yv);
    const float* bp = (cc < 16) ? (bmu + cc) : (bls + (cc - 16));
    float r[8];
    #pragma unroll
    for (int j = 0; j < 8; ++j)
        r[j] = d * (a0[j] + a1[j]) + d * d * yv[j] + bp[j];
    size_t o = (cc < 16) ? ((size_t)node * 16 + cc)
                         : ((size_t)n * 16 + (size_t)node * 16 + (cc - 16));
    *reinterpret_cast<float4*>(outp + o) = make_float4(r[0], r[1], r[2], r[3]);
    *reinterpret_cast<float4*>(outp + o + 4) = make_float4(r[4], r[5], r[6], r[7]);
}

// ----------------------------------------------------------------- matmul
__device__ __forceinline__ void fma4(float4& a, float s, const float4& w) {
    a.x += s * w.x; a.y += s * w.y; a.z += s * w.z; a.w += s * w.w;
}

// Fused multi-W matmul, bf16 weights staged in LDS (thrash-immune, ~6cyc reads).
// out_w[n0..n0+1, c0..c0+3] = X[n0..n0+1, :] @ W_w (+bias on w=0).
// XBF: X rows are bf16 (stride KR elems); OBF: outputs stored bf16.
template <int KR, int PC, int NW, bool XBF, bool OBF, bool BIAS>
__global__ void mml_kernel(const void* __restrict__ Xv, const unsigned int* __restrict__ Wp,
                           const float* __restrict__ bp,
                           void* __restrict__ o0v, void* __restrict__ o1v, int n) {
    constexpr int CP4 = PC / 4;
    constexpr int PCU = PC / 2;
    constexpr int WU = NW * KR * PCU;
    __shared__ __align__(16) unsigned int Wl[WU];
    __shared__ __align__(16) float bl[PC];
    // straight vectorized copy: global images are already in the LDS layout
    {
        const uint4* s4 = reinterpret_cast<const uint4*>(Wp);
        uint4* d4 = reinterpret_cast<uint4*>(Wl);
        for (int i = threadIdx.x; i < WU / 4; i += blockDim.x) d4[i] = s4[i];
        if constexpr (BIAS)
            for (int i = threadIdx.x; i < PC; i += blockDim.x) bl[i] = bp[i];
    }
    __syncthreads();
    int idx = blockIdx.x * blockDim.x + threadIdx.x;
    if (idx >= (n >> 1) * CP4) return;
    int pair = idx / CP4;
    int c0 = (idx - pair * CP4) * 4;
    int n0 = pair * 2;
    const float* xaf = (const float*)Xv + (size_t)n0 * KR;
    const float* xbf = xaf + KR;
    const unsigned short* xah = (const unsigned short*)Xv + (size_t)n0 * KR;
    const unsigned short* xbh = xah + KR;
    const unsigned int* wc = Wl + (c0 >> 1);
    float4 acc[2][NW];
    #pragma unroll
    for (int w = 0; w < NW; ++w) {
        acc[0][w] = make_float4(0.f, 0.f, 0.f, 0.f);
        acc[1][w] = acc[0][w];
    }
    if constexpr (BIAS) {
        acc[0][0] = *reinterpret_cast<const float4*>(&bl[c0]);
        acc[1][0] = acc[0][0];
    }
    #pragma unroll 2
    for (int k4 = 0; k4 < KR / 4; ++k4) {
        float4 va, vb;
        if constexpr (XBF) {
            va = unpack_bf4(*reinterpret_cast<const uint2*>(xah + k4 * 4));
            vb = unpack_bf4(*reinterpret_cast<const uint2*>(xbh + k4 * 4));
        } else {
            va = *reinterpret_cast<const float4*>(xaf + k4 * 4);
            vb = *reinterpret_cast<const float4*>(xbf + k4 * 4);
        }
        #pragma unroll
        for (int j = 0; j < 4; ++j) {
            int k = k4 * 4 + j;
            float sa = (&va.x)[j];
            float sb = (&vb.x)[j];
            #pragma unroll
            for (int w = 0; w < NW; ++w) {
                uint2 q = *reinterpret_cast<const uint2*>(wc + (size_t)(w * KR + k) * PCU);
                float4 wv = unpack_bf4(q);
                fma4(acc[0][w], sa, wv);
                fma4(acc[1][w], sb, wv);
            }
        }
    }
    void* outs[2] = {o0v, o1v};
    #pragma unroll
    for (int w = 0; w < NW; ++w) {
        if constexpr (OBF) {
            unsigned short* o = (unsigned short*)outs[w] + (size_t)n0 * PC + c0;
            *reinterpret_cast<uint2*>(o) =
                make_uint2(pack_bf(acc[0][w].x, acc[0][w].y), pack_bf(acc[0][w].z, acc[0][w].w));
            *reinterpret_cast<uint2*>(o + PC) =
                make_uint2(pack_bf(acc[1][w].x, acc[1][w].y), pack_bf(acc[1][w].z, acc[1][w].w));
        } else {
            float* o = (float*)outs[w] + (size_t)n0 * PC + c0;
            *reinterpret_cast<float4*>(o) = acc[0][w];
            *reinterpret_cast<float4*>(o + PC) = acc[1][w];
        }
    }
}

// ------------------------------------------------------------------ launch

extern "C" void kernel_launch(void* const* d_in, const int* in_sizes, int n_in,
                              void* d_out, int out_size, void* d_ws, size_t ws_size,
                              hipStream_t stream) {
    const float* x   = (const float*)d_in[0];
    const int*   ei  = (const int*)d_in[1];
    const float* W1  = (const float*)d_in[2];
    const float* b1  = (const float*)d_in[3];
    const float* W2  = (const float*)d_in[4];
    const float* b2  = (const float*)d_in[5];
    const float* Wmu = (const float*)d_in[6];
    const float* bmu = (const float*)d_in[7];
    const float* Wls = (const float*)d_in[8];
    const float* bls = (const float*)d_in[9];
    float* out = (float*)d_out;

    const int N = NN, E = EE;
    const int* row = ei;
    const int* col = ei + E;

    // workspace carve-up (256B aligned)
    char* p = (char*)d_ws;
    auto alloc = [&](size_t bytes) -> char* {
        char* r = p;
        p += (bytes + 255) & ~(size_t)255;
        return r;
    };
    int*   deg    = (int*)alloc((size_t)N * 4);
    int*   off    = (int*)alloc((size_t)(N + 1) * 4);
    int*   cursor = (int*)alloc((size_t)N * 4);
    int*   bsum   = (int*)alloc((size_t)256 * 4);
    float* dis    = (float*)alloc((size_t)N * 4);
    float* dis2   = (float*)alloc((size_t)N * 4);
    unsigned int* wB = (unsigned int*)alloc((size_t)TUW * 4);
    float* bB     = (float*)alloc((size_t)NBF * 4);
    unsigned int* eTag = (unsigned int*)alloc((size_t)E * 4);
    unsigned short* y0 = (unsigned short*)alloc((size_t)N * S1 * 2);
    unsigned short* y1 = (unsigned short*)alloc((size_t)N * S1 * 2);
    unsigned short* y2 = (unsigned short*)alloc((size_t)N * S1 * 2);
    unsigned short* y3 = (unsigned short*)alloc((size_t)N * S1 * 2);
    unsigned short* u0 = (unsigned short*)alloc((size_t)N * S2P * 2);
    unsigned short* u1 = (unsigned short*)alloc((size_t)N * S2P * 2);
    unsigned short* u2 = (unsigned short*)alloc((size_t)N * S2P * 2);
    unsigned short* u3 = (unsigned short*)alloc((size_t)N * S2P * 2);
    unsigned short* yh = (unsigned short*)alloc((size_t)N * 32 * 2);

    const unsigned int* W1b = wB;
    const unsigned int* W2b = wB + NU1;
    const unsigned int* Whb = wB + NU1 + NU2;
    const float* b1p = bB;
    const float* b2p = bB + S1;

    const int B = 256;
    int gE = (E + B - 1) / B;
    int nb = (N + SB - 1) / SB;  // 196 scan blocks

    // --- graph preprocessing -> CSR by destination (+ weight repack to bf16)
    hipMemsetAsync(deg, 0, (size_t)N * 4, stream);
    wpad_kernel<<<(TUW + NBF + B - 1) / B, B, 0, stream>>>(W1, b1, W2, b2, Wmu, Wls, wB, bB);
    hist_kernel<<<gE, B, 0, stream>>>(col, deg, E);
    reduce_kernel<<<nb, SB, 0, stream>>>(deg, bsum, N);
    scan_sums_kernel<<<1, SB, 0, stream>>>(bsum, nb);
    block_scan_kernel<<<nb, SB, 0, stream>>>(deg, bsum, off, cursor, dis, dis2, N);
    fill_kernel<<<gE, B, 0, stream>>>(row, col, dis, cursor, eTag, E);

    // grids
    int gm1 = ((N / 2) * (S1 / 4) + B - 1) / B;   // 1758
    int gm2 = ((N / 2) * (S2P / 4) + B - 1) / B;  // 1172
    int gmh = ((N / 2) * 8 + B - 1) / B;          // 782
    int ga72 = (N * (S1 / 8) + B - 1) / B;        // TPN 9
    int ga48 = (N * (S2P / 8) + B - 1) / B;       // TPN 6
    int gaF  = (N * 4 + B - 1) / B;               // TPN 4

    // --- TAG layer 1 via Horner: o1 = relu(y0 + A(y1 + A(y2 + A*y3)))
    mml_kernel<CIN, S1, 2, false, true, true ><<<gm1, B, 0, stream>>>(x, W1b,             b1p, y0, y1, N);
    mml_kernel<CIN, S1, 2, false, true, false><<<gm1, B, 0, stream>>>(x, W1b + 2 * IMG1U, nullptr, y2, y3, N);
    aggw_kernel<S1, true, false><<<ga72, B, 0, stream>>>(y3, y2, y2, off, eTag, N);
    aggw_kernel<S1, true, false><<<ga72, B, 0, stream>>>(y2, y1, y1, off, eTag, N);
    aggw_kernel<S1, true, true ><<<ga72, B, 0, stream>>>(y1, y0, y0, off, eTag, N);
    // o1 = y0 (bf16, stride S1, pad cols zero)

    // --- TAG layer 2 via Horner: o2 = relu(u0 + A(u1 + A(u2 + A*u3)))
    mml_kernel<S1, S2P, 2, true, true, true ><<<gm2, B, 0, stream>>>(y0, W2b,             b2p, u0, u1, N);
    mml_kernel<S1, S2P, 2, true, true, false><<<gm2, B, 0, stream>>>(y0, W2b + 2 * IMG2U, nullptr, u2, u3, N);
    aggw_kernel<S2P, true, false><<<ga48, B, 0, stream>>>(u3, u2, u2, off, eTag, N);
    aggw_kernel<S2P, true, false><<<ga48, B, 0, stream>>>(u2, u1, u1, off, eTag, N);
    aggw_kernel<S2P, true, true ><<<ga48, B, 0, stream>>>(u1, u0, u0, off, eTag, N);
    // o2 = u0 (bf16, stride S2P, pad cols zero)

    // --- GCN heads: head matmul (bf16 in LDS, bf16 out), then fused final agg
    mml_kernel<S2P, 32, 1, true, true, false><<<gmh, B, 0, stream>>>(u0, Whb, nullptr, yh, nullptr, N);
    agg_gcn_final_kernel<<<gaF, B, 0, stream>>>(yh, off, eTag, dis2, bmu, bls, out, N);
}

// Round 12
// 392.122 us; speedup vs baseline: 1.5189x; 1.0034x over previous
//
#include <hip/hip_runtime.h>
#include <hip/hip_fp16.h>

// Problem constants (fixed by the reference)
static constexpr int NN  = 50000;   // nodes (even, < 65536 so src fits u16)
static constexpr int EE  = 800000;  // edges
static constexpr int CIN = 96;      // input channels
static constexpr int L1C = 70, S1 = 72;   // TAG layer 1 out, padded stride (9x16B)
static constexpr int L2C = 43, S2P = 48;  // TAG layer 2 out, padded stride (6x16B)

// bf16 weight image sizes (in uints = 2 bf16)
static constexpr int IMG1U = CIN * S1 / 2;    // 3456
static constexpr int IMG2U = S1 * S2P / 2;    // 1728
static constexpr int IMGHU = S2P * 32 / 2;    // 768
static constexpr int NU1 = 4 * IMG1U;         // 13824
static constexpr int NU2 = 4 * IMG2U;         // 6912
static constexpr int TUW = NU1 + NU2 + IMGHU; // 21504 uints
static constexpr int NBF = S1 + S2P;          // bias floats (72 + 48)

// ------------------------------------------------------------ bf16 helpers
__device__ __forceinline__ float bf_lo(unsigned int u) {
    return __uint_as_float(u << 16);
}
__device__ __forceinline__ float bf_hi(unsigned int u) {
    return __uint_as_float(u & 0xffff0000u);
}
__device__ __forceinline__ unsigned int bf_rne_bits(float f) {
    unsigned int u = __float_as_uint(f);
    return u + 0x7fffu + ((u >> 16) & 1u);
}
__device__ __forceinline__ unsigned int pack_bf(float a, float b) {
    return (bf_rne_bits(a) >> 16) | (bf_rne_bits(b) & 0xffff0000u);
}
__device__ __forceinline__ float4 unpack_bf4(uint2 q) {
    return make_float4(bf_lo(q.x), bf_hi(q.x), bf_lo(q.y), bf_hi(q.y));
}
__device__ __forceinline__ void unpack_bf8(uint4 q, float* f) {
    f[0] = bf_lo(q.x); f[1] = bf_hi(q.x); f[2] = bf_lo(q.y); f[3] = bf_hi(q.y);
    f[4] = bf_lo(q.z); f[5] = bf_hi(q.z); f[6] = bf_lo(q.w); f[7] = bf_hi(q.w);
}

// edge record: src (low 16) | fp16 weight (high 16)
__device__ __forceinline__ int rec_src(unsigned int p) { return (int)(p & 0xffffu); }
__device__ __forceinline__ float rec_w(unsigned int p) {
    return __half2float(__ushort_as_half((unsigned short)(p >> 16)));
}

// ---------------------------------------------------------------- preprocessing

__global__ void hist_kernel(const int* __restrict__ col, int* __restrict__ deg, int E) {
    int e = blockIdx.x * blockDim.x + threadIdx.x;
    if (e < E) atomicAdd(&deg[col[e]], 1);
}

static constexpr int SB = 256;  // scan block size

__global__ void reduce_kernel(const int* __restrict__ deg, int* __restrict__ bsum, int n) {
    __shared__ int sd[SB];
    int i = blockIdx.x * SB + threadIdx.x;
    sd[threadIdx.x] = (i < n) ? deg[i] : 0;
    __syncthreads();
    for (int s = SB / 2; s > 0; s >>= 1) {
        if (threadIdx.x < s) sd[threadIdx.x] += sd[threadIdx.x + s];
        __syncthreads();
    }
    if (threadIdx.x == 0) bsum[blockIdx.x] = sd[0];
}

__global__ void scan_sums_kernel(int* __restrict__ bsum, int nb) {
    __shared__ int sd[SB];
    int v = (threadIdx.x < nb) ? bsum[threadIdx.x] : 0;
    sd[threadIdx.x] = v;
    __syncthreads();
    for (int s = 1; s < SB; s <<= 1) {
        int t = (threadIdx.x >= s) ? sd[threadIdx.x - s] : 0;
        __syncthreads();
        sd[threadIdx.x] += t;
        __syncthreads();
    }
    if (threadIdx.x < nb) bsum[threadIdx.x] = sd[threadIdx.x] - v;  // exclusive
}

__global__ void block_scan_kernel(const int* __restrict__ deg, const int* __restrict__ bsum,
                                  int* __restrict__ off, int* __restrict__ cursor,
                                  float* __restrict__ dis, float* __restrict__ dis2, int n) {
    __shared__ int sd[SB];
    int i = blockIdx.x * SB + threadIdx.x;
    int v = (i < n) ? deg[i] : 0;
    sd[threadIdx.x] = v;
    __syncthreads();
    for (int s = 1; s < SB; s <<= 1) {
        int t = (threadIdx.x >= s) ? sd[threadIdx.x - s] : 0;
        __syncthreads();
        sd[threadIdx.x] += t;
        __syncthreads();
    }
    if (i < n) {
        int e = bsum[blockIdx.x] + sd[threadIdx.x] - v;
        off[i] = e;
        cursor[i] = e;
        dis[i]  = (v > 0) ? rsqrtf((float)v) : 0.0f;
        dis2[i] = rsqrtf((float)v + 1.0f);
        if (i == n - 1) off[n] = e + v;
    }
}

// Destination-sliced fill: 8 node slices; blocks with blockIdx%8==s handle only
// slice s. Dispatch round-robins blocks over the 8 XCDs, so each eTag line is
// (mostly) dirtied by a single XCD's L2 and written back ONCE fully assembled.
// r11 evidence: cross-XCD interleaved 4B scatter -> 55MB partial-line writebacks
// for 3.2MB of data. Correctness never depends on the block->XCD mapping.
static constexpr int NSLICE = 8;
static constexpr int SLICEN = NN / NSLICE;  // 6250

__global__ void fill_kernel(const int* __restrict__ row, const int* __restrict__ col,
                            const float* __restrict__ dis, int* __restrict__ cursor,
                            unsigned int* __restrict__ eTag, int E) {
    int s = blockIdx.x & (NSLICE - 1);
    int nlo = s * SLICEN, nhi = nlo + SLICEN;
    int stride = (gridDim.x >> 3) * blockDim.x;
    for (int e = (blockIdx.x >> 3) * blockDim.x + threadIdx.x; e < E; e += stride) {
        int c = col[e];
        if (c >= nlo && c < nhi) {
            int r = row[e];
            int pos = atomicAdd(&cursor[c], 1);
            unsigned short h = __half_as_ushort(__float2half(dis[r] * dis[c]));
            eTag[pos] = (unsigned int)r | ((unsigned int)h << 16);
        }
    }
}

// repack weights into padded bf16 global images + padded fp32 biases
__global__ void wpad_kernel(const float* __restrict__ W1, const float* __restrict__ b1,
                            const float* __restrict__ W2, const float* __restrict__ b2,
                            const float* __restrict__ Wmu, const float* __restrict__ Wls,
                            unsigned int* __restrict__ wB, float* __restrict__ bB) {
    int i = blockIdx.x * blockDim.x + threadIdx.x;
    if (i < TUW) {
        float v0 = 0.f, v1 = 0.f;
        if (i < NU1) {
            int img = i / IMG1U, r = i - img * IMG1U;
            int k = r / (S1 / 2), c0 = (r - k * (S1 / 2)) * 2;
            const float* Wi = W1 + (size_t)img * CIN * L1C + (size_t)k * L1C;
            if (c0 < L1C) v0 = Wi[c0];
            if (c0 + 1 < L1C) v1 = Wi[c0 + 1];
        } else if (i < NU1 + NU2) {
            int j = i - NU1;
            int img = j / IMG2U, r = j - img * IMG2U;
            int k = r / (S2P / 2), c0 = (r - k * (S2P / 2)) * 2;
            if (k < L1C) {
                const float* Wi = W2 + (size_t)img * L1C * L2C + (size_t)k * L2C;
                if (c0 < L2C) v0 = Wi[c0];
                if (c0 + 1 < L2C) v1 = Wi[c0 + 1];
            }
        } else {
            int j = i - NU1 - NU2;
            int k = j / 16, c0 = (j - k * 16) * 2;  // 32 cols -> 16 uints per row
            if (k < L2C) {
                v0 = (c0 < 16) ? Wmu[k * 16 + c0] : Wls[k * 16 + (c0 - 16)];
                int c1 = c0 + 1;
                v1 = (c1 < 16) ? Wmu[k * 16 + c1] : Wls[k * 16 + (c1 - 16)];
            }
        }
        wB[i] = pack_bf(v0, v1);
    } else if (i < TUW + NBF) {
        int j = i - TUW;
        float v = 0.f;
        if (j < S1) { if (j < L1C) v = b1[j]; }
        else { int k = j - S1; if (k < L2C) v = b2[k]; }
        bB[j] = v;
    }
}

// ------------------------------------------------------------- aggregation (bf16)
// Wide-gather variant: thread = (node, 8-channel group) -> one uint4 (16B) per
// edge gather, halving the L2 request count vs 8B.
// out[i][:] = (HASADD ? addv[i][:] : 0) + sum_e w_e * in[src_e][:]  (+ ReLU)
template <int C, bool HASADD, bool RELU>
__global__ void aggw_kernel(const unsigned short* __restrict__ in, const unsigned short* addv,
                            unsigned short* out, const int* __restrict__ off,
                            const unsigned int* __restrict__ ep, int n) {
    constexpr int TPN = C / 8;  // threads per node (8 bf16 channels each)
    int t = blockIdx.x * blockDim.x + threadIdx.x;
    if (t >= n * TPN) return;
    int node = t / TPN;
    int cc = (t - node * TPN) * 8;
    int beg = off[node], end = off[node + 1];
    float a0[8], a1[8];
    #pragma unroll
    for (int j = 0; j < 8; ++j) { a0[j] = 0.f; a1[j] = 0.f; }
    int e = beg;
    for (; e + 4 <= end; e += 4) {
        unsigned int p0 = ep[e], p1 = ep[e + 1], p2 = ep[e + 2], p3 = ep[e + 3];
        float w0 = rec_w(p0), w1 = rec_w(p1), w2 = rec_w(p2), w3 = rec_w(p3);
        uint4 q0 = *reinterpret_cast<const uint4*>(in + (size_t)rec_src(p0) * C + cc);
        uint4 q1 = *reinterpret_cast<const uint4*>(in + (size_t)rec_src(p1) * C + cc);
        uint4 q2 = *reinterpret_cast<const uint4*>(in + (size_t)rec_src(p2) * C + cc);
        uint4 q3 = *reinterpret_cast<const uint4*>(in + (size_t)rec_src(p3) * C + cc);
        float f[8];
        unpack_bf8(q0, f);
        #pragma unroll
        for (int j = 0; j < 8; ++j) a0[j] += w0 * f[j];
        unpack_bf8(q1, f);
        #pragma unroll
        for (int j = 0; j < 8; ++j) a1[j] += w1 * f[j];
        unpack_bf8(q2, f);
        #pragma unroll
        for (int j = 0; j < 8; ++j) a0[j] += w2 * f[j];
        unpack_bf8(q3, f);
        #pragma unroll
        for (int j = 0; j < 8; ++j) a1[j] += w3 * f[j];
    }
    for (; e < end; ++e) {
        unsigned int p = ep[e];
        float w = rec_w(p);
        uint4 q = *reinterpret_cast<const uint4*>(in + (size_t)rec_src(p) * C + cc);
        float f[8];
        unpack_bf8(q, f);
        #pragma unroll
        for (int j = 0; j < 8; ++j) a0[j] += w * f[j];
    }
    float r[8];
    #pragma unroll
    for (int j = 0; j < 8; ++j) r[j] = a0[j] + a1[j];
    if constexpr (HASADD) {
        uint4 qa = *reinterpret_cast<const uint4*>(addv + (size_t)node * C + cc);
        float f[8];
        unpack_bf8(qa, f);
        #pragma unroll
        for (int j = 0; j < 8; ++j) r[j] += f[j];
    }
    if constexpr (RELU) {
        #pragma unroll
        for (int j = 0; j < 8; ++j) r[j] = fmaxf(r[j], 0.f);
    }
    uint4 o;
    o.x = pack_bf(r[0], r[1]); o.y = pack_bf(r[2], r[3]);
    o.z = pack_bf(r[4], r[5]); o.w = pack_bf(r[6], r[7]);
    *reinterpret_cast<uint4*>(out + (size_t)node * C + cc) = o;
}

// GCN agg + self-loop + bias + split-store, fused final stage. bf16 yh, 16B
// gathers (4 threads/node x 8 channels); GCN edge weight from dis2 table.
__global__ void agg_gcn_final_kernel(const unsigned short* __restrict__ yh,
                                     const int* __restrict__ off,
                                     const unsigned int* __restrict__ ep,
                                     const float* __restrict__ dis2,
                                     const float* __restrict__ bmu,
                                     const float* __restrict__ bls,
                                     float* __restrict__ outp, int n) {
    int t = blockIdx.x * blockDim.x + threadIdx.x;
    if (t >= n * 4) return;
    int node = t >> 2;
    int cc = (t & 3) * 8;
    int beg = off[node], end = off[node + 1];
    float a0[8], a1[8];
    #pragma unroll
    for (int j = 0; j < 8; ++j) { a0[j] = 0.f; a1[j] = 0.f; }
    int e = beg;
    for (; e + 2 <= end; e += 2) {
        int s0 = rec_src(ep[e]), s1 = rec_src(ep[e + 1]);
        float w0 = dis2[s0], w1 = dis2[s1];
        uint4 q0 = *reinterpret_cast<const uint4*>(yh + (size_t)s0 * 32 + cc);
        uint4 q1 = *reinterpret_cast<const uint4*>(yh + (size_t)s1 * 32 + cc);
        float f[8];
        unpack_bf8(q0, f);
        #pragma unroll
        for (int j = 0; j < 8; ++j) a0[j] += w0 * f[j];
        unpack_bf8(q1, f);
        #pragma unroll
        for (int j = 0; j < 8; ++j) a1[j] += w1 * f[j];
    }
    for (; e < end; ++e) {
        int s = rec_src(ep[e]);
        float w = dis2[s];
        uint4 q = *reinterpret_cast<const uint4*>(yh + (size_t)s * 32 + cc);
        float f[8];
        unpack_bf8(q, f);
        #pragma unroll
        for (int j = 0; j < 8; ++j) a0[j] += w * f[j];
    }
    float d = dis2[node];
    uint4 qy = *reinterpret_cast<const uint4*>(yh + (size_t)node * 32 + cc);
    float yv[8];
    unpack_bf8(qy, yv);
    const float* bp = (cc < 16) ? (bmu + cc) : (bls + (cc - 16));
    float r[8];
    #pragma unroll
    for (int j = 0; j < 8; ++j)
        r[j] = d * (a0[j] + a1[j]) + d * d * yv[j] + bp[j];
    size_t o = (cc < 16) ? ((size_t)node * 16 + cc)
                         : ((size_t)n * 16 + (size_t)node * 16 + (cc - 16));
    *reinterpret_cast<float4*>(outp + o) = make_float4(r[0], r[1], r[2], r[3]);
    *reinterpret_cast<float4*>(outp + o + 4) = make_float4(r[4], r[5], r[6], r[7]);
}

// ----------------------------------------------------------------- matmul
__device__ __forceinline__ void fma4(float4& a, float s, const float4& w) {
    a.x += s * w.x; a.y += s * w.y; a.z += s * w.z; a.w += s * w.w;
}

// Fused multi-W matmul, bf16 weights staged in LDS (thrash-immune, ~6cyc reads).
// out_w[n0..n0+1, c0..c0+3] = X[n0..n0+1, :] @ W_w (+bias on w=0).
// XBF: X rows are bf16 (stride KR elems); OBF: outputs stored bf16.
template <int KR, int PC, int NW, bool XBF, bool OBF, bool BIAS>
__global__ void mml_kernel(const void* __restrict__ Xv, const unsigned int* __restrict__ Wp,
                           const float* __restrict__ bp,
                           void* __restrict__ o0v, void* __restrict__ o1v, int n) {
    constexpr int CP4 = PC / 4;
    constexpr int PCU = PC / 2;
    constexpr int WU = NW * KR * PCU;
    __shared__ __align__(16) unsigned int Wl[WU];
    __shared__ __align__(16) float bl[PC];
    // straight vectorized copy: global images are already in the LDS layout
    {
        const uint4* s4 = reinterpret_cast<const uint4*>(Wp);
        uint4* d4 = reinterpret_cast<uint4*>(Wl);
        for (int i = threadIdx.x; i < WU / 4; i += blockDim.x) d4[i] = s4[i];
        if constexpr (BIAS)
            for (int i = threadIdx.x; i < PC; i += blockDim.x) bl[i] = bp[i];
    }
    __syncthreads();
    int idx = blockIdx.x * blockDim.x + threadIdx.x;
    if (idx >= (n >> 1) * CP4) return;
    int pair = idx / CP4;
    int c0 = (idx - pair * CP4) * 4;
    int n0 = pair * 2;
    const float* xaf = (const float*)Xv + (size_t)n0 * KR;
    const float* xbf = xaf + KR;
    const unsigned short* xah = (const unsigned short*)Xv + (size_t)n0 * KR;
    const unsigned short* xbh = xah + KR;
    const unsigned int* wc = Wl + (c0 >> 1);
    float4 acc[2][NW];
    #pragma unroll
    for (int w = 0; w < NW; ++w) {
        acc[0][w] = make_float4(0.f, 0.f, 0.f, 0.f);
        acc[1][w] = acc[0][w];
    }
    if constexpr (BIAS) {
        acc[0][0] = *reinterpret_cast<const float4*>(&bl[c0]);
        acc[1][0] = acc[0][0];
    }
    #pragma unroll 2
    for (int k4 = 0; k4 < KR / 4; ++k4) {
        float4 va, vb;
        if constexpr (XBF) {
            va = unpack_bf4(*reinterpret_cast<const uint2*>(xah + k4 * 4));
            vb = unpack_bf4(*reinterpret_cast<const uint2*>(xbh + k4 * 4));
        } else {
            va = *reinterpret_cast<const float4*>(xaf + k4 * 4);
            vb = *reinterpret_cast<const float4*>(xbf + k4 * 4);
        }
        #pragma unroll
        for (int j = 0; j < 4; ++j) {
            int k = k4 * 4 + j;
            float sa = (&va.x)[j];
            float sb = (&vb.x)[j];
            #pragma unroll
            for (int w = 0; w < NW; ++w) {
                uint2 q = *reinterpret_cast<const uint2*>(wc + (size_t)(w * KR + k) * PCU);
                float4 wv = unpack_bf4(q);
                fma4(acc[0][w], sa, wv);
                fma4(acc[1][w], sb, wv);
            }
        }
    }
    void* outs[2] = {o0v, o1v};
    #pragma unroll
    for (int w = 0; w < NW; ++w) {
        if constexpr (OBF) {
            unsigned short* o = (unsigned short*)outs[w] + (size_t)n0 * PC + c0;
            *reinterpret_cast<uint2*>(o) =
                make_uint2(pack_bf(acc[0][w].x, acc[0][w].y), pack_bf(acc[0][w].z, acc[0][w].w));
            *reinterpret_cast<uint2*>(o + PC) =
                make_uint2(pack_bf(acc[1][w].x, acc[1][w].y), pack_bf(acc[1][w].z, acc[1][w].w));
        } else {
            float* o = (float*)outs[w] + (size_t)n0 * PC + c0;
            *reinterpret_cast<float4*>(o) = acc[0][w];
            *reinterpret_cast<float4*>(o + PC) = acc[1][w];
        }
    }
}

// ------------------------------------------------------------------ launch

extern "C" void kernel_launch(void* const* d_in, const int* in_sizes, int n_in,
                              void* d_out, int out_size, void* d_ws, size_t ws_size,
                              hipStream_t stream) {
    const float* x   = (const float*)d_in[0];
    const int*   ei  = (const int*)d_in[1];
    const float* W1  = (const float*)d_in[2];
    const float* b1  = (const float*)d_in[3];
    const float* W2  = (const float*)d_in[4];
    const float* b2  = (const float*)d_in[5];
    const float* Wmu = (const float*)d_in[6];
    const float* bmu = (const float*)d_in[7];
    const float* Wls = (const float*)d_in[8];
    const float* bls = (const float*)d_in[9];
    float* out = (float*)d_out;

    const int N = NN, E = EE;
    const int* row = ei;
    const int* col = ei + E;

    // workspace carve-up (256B aligned)
    char* p = (char*)d_ws;
    auto alloc = [&](size_t bytes) -> char* {
        char* r = p;
        p += (bytes + 255) & ~(size_t)255;
        return r;
    };
    int*   deg    = (int*)alloc((size_t)N * 4);
    int*   off    = (int*)alloc((size_t)(N + 1) * 4);
    int*   cursor = (int*)alloc((size_t)N * 4);
    int*   bsum   = (int*)alloc((size_t)256 * 4);
    float* dis    = (float*)alloc((size_t)N * 4);
    float* dis2   = (float*)alloc((size_t)N * 4);
    unsigned int* wB = (unsigned int*)alloc((size_t)TUW * 4);
    float* bB     = (float*)alloc((size_t)NBF * 4);
    unsigned int* eTag = (unsigned int*)alloc((size_t)E * 4);
    unsigned short* y0 = (unsigned short*)alloc((size_t)N * S1 * 2);
    unsigned short* y1 = (unsigned short*)alloc((size_t)N * S1 * 2);
    unsigned short* y2 = (unsigned short*)alloc((size_t)N * S1 * 2);
    unsigned short* y3 = (unsigned short*)alloc((size_t)N * S1 * 2);
    unsigned short* u0 = (unsigned short*)alloc((size_t)N * S2P * 2);
    unsigned short* u1 = (unsigned short*)alloc((size_t)N * S2P * 2);
    unsigned short* u2 = (unsigned short*)alloc((size_t)N * S2P * 2);
    unsigned short* u3 = (unsigned short*)alloc((size_t)N * S2P * 2);
    unsigned short* yh = (unsigned short*)alloc((size_t)N * 32 * 2);

    const unsigned int* W1b = wB;
    const unsigned int* W2b = wB + NU1;
    const unsigned int* Whb = wB + NU1 + NU2;
    const float* b1p = bB;
    const float* b2p = bB + S1;

    const int B = 256;
    int gE = (E + B - 1) / B;
    int nb = (N + SB - 1) / SB;  // 196 scan blocks

    // --- graph preprocessing -> CSR by destination (+ weight repack to bf16)
    hipMemsetAsync(deg, 0, (size_t)N * 4, stream);
    wpad_kernel<<<(TUW + NBF + B - 1) / B, B, 0, stream>>>(W1, b1, W2, b2, Wmu, Wls, wB, bB);
    hist_kernel<<<gE, B, 0, stream>>>(col, deg, E);
    reduce_kernel<<<nb, SB, 0, stream>>>(deg, bsum, N);
    scan_sums_kernel<<<1, SB, 0, stream>>>(bsum, nb);
    block_scan_kernel<<<nb, SB, 0, stream>>>(deg, bsum, off, cursor, dis, dis2, N);
    fill_kernel<<<3200, B, 0, stream>>>(row, col, dis, cursor, eTag, E);  // 8 slices x 400 blocks

    // grids
    int gm1 = ((N / 2) * (S1 / 4) + B - 1) / B;   // 1758
    int gm2 = ((N / 2) * (S2P / 4) + B - 1) / B;  // 1172
    int gmh = ((N / 2) * 8 + B - 1) / B;          // 782
    int ga72 = (N * (S1 / 8) + B - 1) / B;        // TPN 9
    int ga48 = (N * (S2P / 8) + B - 1) / B;       // TPN 6
    int gaF  = (N * 4 + B - 1) / B;               // TPN 4

    // --- TAG layer 1 via Horner: o1 = relu(y0 + A(y1 + A(y2 + A*y3)))
    mml_kernel<CIN, S1, 2, false, true, true ><<<gm1, B, 0, stream>>>(x, W1b,             b1p, y0, y1, N);
    mml_kernel<CIN, S1, 2, false, true, false><<<gm1, B, 0, stream>>>(x, W1b + 2 * IMG1U, nullptr, y2, y3, N);
    aggw_kernel<S1, true, false><<<ga72, B, 0, stream>>>(y3, y2, y2, off, eTag, N);
    aggw_kernel<S1, true, false><<<ga72, B, 0, stream>>>(y2, y1, y1, off, eTag, N);
    aggw_kernel<S1, true, true ><<<ga72, B, 0, stream>>>(y1, y0, y0, off, eTag, N);
    // o1 = y0 (bf16, stride S1, pad cols zero)

    // --- TAG layer 2 via Horner: o2 = relu(u0 + A(u1 + A(u2 + A*u3)))
    mml_kernel<S1, S2P, 2, true, true, true ><<<gm2, B, 0, stream>>>(y0, W2b,             b2p, u0, u1, N);
    mml_kernel<S1, S2P, 2, true, true, false><<<gm2, B, 0, stream>>>(y0, W2b + 2 * IMG2U, nullptr, u2, u3, N);
    aggw_kernel<S2P, true, false><<<ga48, B, 0, stream>>>(u3, u2, u2, off, eTag, N);
    aggw_kernel<S2P, true, false><<<ga48, B, 0, stream>>>(u2, u1, u1, off, eTag, N);
    aggw_kernel<S2P, true, true ><<<ga48, B, 0, stream>>>(u1, u0, u0, off, eTag, N);
    // o2 = u0 (bf16, stride S2P, pad cols zero)

    // --- GCN heads: head matmul (bf16 in LDS, bf16 out), then fused final agg
    mml_kernel<S2P, 32, 1, true, true, false><<<gmh, B, 0, stream>>>(u0, Whb, nullptr, yh, nullptr, N);
    agg_gcn_final_kernel<<<gaF, B, 0, stream>>>(yh, off, eTag, dis2, bmu, bls, out, N);
}